// Round 5
// baseline (861.504 us; speedup 1.0000x reference)
//
#include <hip/hip_runtime.h>
#include <math.h>

// Problem constants (B=4, S=512, H=2048, E=16, K=4)
#define M_TOK 2048
#define H_    2048
#define H2_   1024
#define E_    16
#define CAP_  768
#define ALPHA_ 0.7f
#define WSCALE 64.0f
#define INV_WSCALE (1.0f / 64.0f)

typedef _Float16 half8 __attribute__((ext_vector_type(8)));
typedef float f32x4 __attribute__((ext_vector_type(4)));

typedef __attribute__((address_space(1))) const unsigned int* gas_ptr;
typedef __attribute__((address_space(3))) unsigned int* las_ptr;

__device__ __forceinline__ void load_lds16(const void* g, void* l) {
    __builtin_amdgcn_global_load_lds((gas_ptr)g, (las_ptr)l, 16, 0, 0);
}

// split 8 fp32 -> half8 hi + half8 lo
__device__ __forceinline__ void split8(const f32x4 a, const f32x4 b,
                                       half8* hi, half8* lo) {
#pragma unroll
    for (int i = 0; i < 4; ++i) {
        _Float16 h0 = (_Float16)a[i];
        (*hi)[i] = h0;
        (*lo)[i] = (_Float16)(a[i] - (float)h0);
        _Float16 h1 = (_Float16)b[i];
        (*hi)[i + 4] = h1;
        (*lo)[i + 4] = (_Float16)(b[i] - (float)h1);
    }
}

// ---------------------------------------------------------------------------
// Activation split: fp32 [M,K] -> f16 hi/lo [M,K] (unscaled, row-major kept)
// ---------------------------------------------------------------------------
struct ADesc { const float* A; _Float16* oh; _Float16* ol; };
struct APack { ADesc g[3]; };

__global__ __launch_bounds__(256) void asplit_kernel(APack pack)
{
    ADesc d;
    switch (blockIdx.z) {
        case 0: d = pack.g[0]; break;
        case 1: d = pack.g[1]; break;
        default: d = pack.g[2]; break;
    }
    const size_t i = ((size_t)blockIdx.x * 256 + threadIdx.x) * 8;
    f32x4 v0 = *(const f32x4*)(d.A + i);
    f32x4 v1 = *(const f32x4*)(d.A + i + 4);
    half8 h, l;
    split8(v0, v1, &h, &l);
    *(half8*)(d.oh + i) = h;
    *(half8*)(d.ol + i) = l;
}

// ---------------------------------------------------------------------------
// Weight split+transpose: W fp32 [K,N] -> Wt_h/Wt_l f16 [N,K], scaled by 64.
// ---------------------------------------------------------------------------
struct WDesc { const float* W; _Float16* oh; _Float16* ol; int K; int N; };
struct WPack { WDesc g[7]; };

__global__ __launch_bounds__(256) void wsplit_kernel(WPack pack)
{
    WDesc d;
    switch (blockIdx.z) {
        case 0: d = pack.g[0]; break;
        case 1: d = pack.g[1]; break;
        case 2: d = pack.g[2]; break;
        case 3: d = pack.g[3]; break;
        case 4: d = pack.g[4]; break;
        case 5: d = pack.g[5]; break;
        default: d = pack.g[6]; break;
    }
    const int n0 = blockIdx.y * 64;
    if (n0 >= d.N) return;
    const int k0 = blockIdx.x * 64;

    __shared__ float T[64][68];
    const int t = threadIdx.x;

    {
        const int kr = t >> 2;
        const int c0 = (t & 3) << 4;
        const float* src = d.W + (size_t)(k0 + kr) * d.N + n0 + c0;
        f32x4 v0 = *(const f32x4*)(src);
        f32x4 v1 = *(const f32x4*)(src + 4);
        f32x4 v2 = *(const f32x4*)(src + 8);
        f32x4 v3 = *(const f32x4*)(src + 12);
#pragma unroll
        for (int i = 0; i < 4; ++i) T[c0 + i][kr]      = v0[i];
#pragma unroll
        for (int i = 0; i < 4; ++i) T[c0 + 4 + i][kr]  = v1[i];
#pragma unroll
        for (int i = 0; i < 4; ++i) T[c0 + 8 + i][kr]  = v2[i];
#pragma unroll
        for (int i = 0; i < 4; ++i) T[c0 + 12 + i][kr] = v3[i];
    }
    __syncthreads();

    {
        const int n  = t >> 2;
        const int kj = (t & 3) << 4;
        half8 h0, l0, h1, l1;
        f32x4 u0 = *(const f32x4*)&T[n][kj];
        f32x4 u1 = *(const f32x4*)&T[n][kj + 4];
        f32x4 u2 = *(const f32x4*)&T[n][kj + 8];
        f32x4 u3 = *(const f32x4*)&T[n][kj + 12];
        u0 *= WSCALE; u1 *= WSCALE; u2 *= WSCALE; u3 *= WSCALE;
        split8(u0, u1, &h0, &l0);
        split8(u2, u3, &h1, &l1);
        const size_t o = (size_t)(n0 + n) * d.K + k0 + kj;
        *(half8*)(d.oh + o)     = h0;
        *(half8*)(d.oh + o + 8) = h1;
        *(half8*)(d.ol + o)     = l0;
        *(half8*)(d.ol + o + 8) = l1;
    }
}

// ---------------------------------------------------------------------------
// f16x3 MFMA GEMM, both operands pre-split f16 [rows,K].
// Block 256x128, BK=32, 4 waves x (128x64 = 8x4 tiles of 16x16x32).
// All staging via global_load_lds (swizzled granules, 0 bank conflicts).
// mode 0: fp32 out; mode 1: f16 hi/lo out (for chained GEMMs).
// ---------------------------------------------------------------------------
struct GDesc {
    const _Float16* Ah; const _Float16* Al;
    const _Float16* Wh; const _Float16* Wl;
    const float* bias; float* Cf; _Float16* Ch; _Float16* Cl;
    int K; int N; int ntn; int relu; int mode;
};
struct GPack { GDesc g[4]; };

__global__ __launch_bounds__(256) void gemm_mfma_kernel(GPack pack)
{
    GDesc d;
    switch (blockIdx.z) {
        case 0: d = pack.g[0]; break;
        case 1: d = pack.g[1]; break;
        case 2: d = pack.g[2]; break;
        default: d = pack.g[3]; break;
    }
    const int nt_ = blockIdx.x;
    if (nt_ >= d.ntn) return;
    const int bm = blockIdx.y * 256;
    const int bn = nt_ * 128;
    const int K = d.K, N = d.N;

    // granule layout: slot g holds (row = g>>2, q = ((g&3) - (row>>1))&3);
    // fragment read of granule (row,q) at slot row*4 + ((q + (row>>1))&3)
    // -> every b128 access <=2-way (free). [verified 0 conflicts in R4]
    __shared__ _Float16 Ah_s[256 * 32];   // 16 KB
    __shared__ _Float16 Al_s[256 * 32];   // 16 KB
    __shared__ _Float16 Bh_s[128 * 32];   // 8 KB
    __shared__ _Float16 Bl_s[128 * 32];   // 8 KB

    const int tid  = threadIdx.x;
    const int lane = tid & 63;
    const int wave = tid >> 6;
    const int wm = wave >> 1, wn = wave & 1;

    // staging maps
    int a_row[4], a_q[4];
#pragma unroll
    for (int is = 0; is < 4; ++is) {
        const int g = tid + (is << 8);
        a_row[is] = g >> 2;
        a_q[is]   = ((g & 3) - (a_row[is] >> 1)) & 3;
    }
    int b_row[2], b_q[2];
#pragma unroll
    for (int is = 0; is < 2; ++is) {
        const int g = tid + (is << 8);
        b_row[is] = g >> 2;
        b_q[is]   = ((g & 3) - (b_row[is] >> 1)) & 3;
    }

    // fragment read offsets (mt/nt step of 16 rows keeps swizzle class)
    const int am0  = wm * 128 + (lane & 15);
    const int aoff = (am0 * 4 + (((lane >> 4) + (am0 >> 1)) & 3)) * 8;
    const int bn0  = wn * 64 + (lane & 15);
    const int boff = (bn0 * 4 + (((lane >> 4) + (bn0 >> 1)) & 3)) * 8;

    f32x4 acc[8][4];
#pragma unroll
    for (int i = 0; i < 8; ++i)
#pragma unroll
        for (int j = 0; j < 4; ++j) acc[i][j] = (f32x4)0.f;

    for (int k0 = 0; k0 < K; k0 += 32) {
        if (k0) __syncthreads();   // prev tile fully consumed

#pragma unroll
        for (int is = 0; is < 4; ++is) {
            const size_t go = (size_t)(bm + a_row[is]) * K + k0 + a_q[is] * 8;
            load_lds16(d.Ah + go, &Ah_s[(size_t)(tid + (is << 8)) * 8]);
            load_lds16(d.Al + go, &Al_s[(size_t)(tid + (is << 8)) * 8]);
        }
#pragma unroll
        for (int is = 0; is < 2; ++is) {
            const size_t go = (size_t)(bn + b_row[is]) * K + k0 + b_q[is] * 8;
            load_lds16(d.Wh + go, &Bh_s[(size_t)(tid + (is << 8)) * 8]);
            load_lds16(d.Wl + go, &Bl_s[(size_t)(tid + (is << 8)) * 8]);
        }

        __syncthreads();   // drains DMA (vmcnt) before reads

        half8 fAh[8], fAl[8];
#pragma unroll
        for (int mt = 0; mt < 8; ++mt) {
            fAh[mt] = *(const half8*)&Ah_s[aoff + mt * 512];
            fAl[mt] = *(const half8*)&Al_s[aoff + mt * 512];
        }
#pragma unroll
        for (int nt = 0; nt < 4; ++nt) {
            half8 fBh = *(const half8*)&Bh_s[boff + nt * 512];
            half8 fBl = *(const half8*)&Bl_s[boff + nt * 512];
#pragma unroll
            for (int mt = 0; mt < 8; ++mt) {
                acc[mt][nt] = __builtin_amdgcn_mfma_f32_16x16x32_f16(
                    fAh[mt], fBh, acc[mt][nt], 0, 0, 0);
                acc[mt][nt] = __builtin_amdgcn_mfma_f32_16x16x32_f16(
                    fAh[mt], fBl, acc[mt][nt], 0, 0, 0);
                acc[mt][nt] = __builtin_amdgcn_mfma_f32_16x16x32_f16(
                    fAl[mt], fBh, acc[mt][nt], 0, 0, 0);
            }
        }
    }

    // epilogue: C/D layout col=lane&15, row=(lane>>4)*4+reg
    const int erow0 = bm + wm * 128 + ((lane >> 4) << 2);
    const int ecol0 = bn + wn * 64 + (lane & 15);
#pragma unroll
    for (int nt = 0; nt < 4; ++nt) {
        const int col = ecol0 + nt * 16;
        const float bb = d.bias[col];
#pragma unroll
        for (int mt = 0; mt < 8; ++mt) {
            f32x4 a = acc[mt][nt];
#pragma unroll
            for (int r = 0; r < 4; ++r) {
                float v = a[r] * INV_WSCALE + bb;
                if (d.relu) v = fmaxf(v, 0.f);
                const size_t o = (size_t)(erow0 + mt * 16 + r) * N + col;
                if (d.mode == 0) {
                    d.Cf[o] = v;
                } else {
                    _Float16 h = (_Float16)v;
                    d.Ch[o] = h;
                    d.Cl[o] = (_Float16)(v - (float)h);
                }
            }
        }
    }
}

// ---------------------------------------------------------------------------
// Batched skinny GEMM: C[M,16] = A[M,K] @ W[K,16] + bias[16]   (fp32)
// ---------------------------------------------------------------------------
struct SDesc { const float* A; const float* W; const float* bias; float* C; int K; };
struct SPack { SDesc g[5]; };

__global__ __launch_bounds__(256) void gemm_n16_kernel(SPack pack)
{
    SDesc d;
    switch (blockIdx.z) {
        case 0: d = pack.g[0]; break;
        case 1: d = pack.g[1]; break;
        case 2: d = pack.g[2]; break;
        case 3: d = pack.g[3]; break;
        default: d = pack.g[4]; break;
    }
    __shared__ float As[16][68];
    __shared__ float Ws[64][16];

    const int tid = threadIdx.x;
    const int e = tid & 15;
    const int r = tid >> 4;
    const int row0 = blockIdx.x * 16;

    const int lr  = tid >> 4;
    const int lk4 = (tid & 15) << 2;
    const int wk  = tid >> 2;
    const int we4 = (tid & 3) << 2;

    const int K = d.K;
    float acc = 0.f;
    for (int k0 = 0; k0 < K; k0 += 64) {
        float4 av = *(const float4*)&d.A[(size_t)(row0 + lr) * K + k0 + lk4];
        float4 wv = *(const float4*)&d.W[(size_t)(k0 + wk) * E_ + we4];
        if (k0) __syncthreads();
        *(float4*)&As[lr][lk4] = av;
        *(float4*)&Ws[wk][we4] = wv;
        __syncthreads();
#pragma unroll
        for (int kk = 0; kk < 64; kk += 4) {
            float4 a = *(const float4*)&As[r][kk];
            acc = fmaf(a.x, Ws[kk + 0][e], acc);
            acc = fmaf(a.y, Ws[kk + 1][e], acc);
            acc = fmaf(a.z, Ws[kk + 2][e], acc);
            acc = fmaf(a.w, Ws[kk + 3][e], acc);
        }
    }
    d.C[(size_t)(row0 + r) * E_ + e] = acc + d.bias[e];
}

// ---------------------------------------------------------------------------
// Router finalize
// ---------------------------------------------------------------------------
__device__ __forceinline__ void softmax16_acc(const float* __restrict__ lg,
                                              float w, float* __restrict__ p)
{
    float mx = lg[0];
#pragma unroll
    for (int e = 1; e < 16; ++e) mx = fmaxf(mx, lg[e]);
    float ex[16];
    float s = 0.f;
#pragma unroll
    for (int e = 0; e < 16; ++e) { ex[e] = expf(lg[e] - mx); s += ex[e]; }
    const float wi = w / s;
#pragma unroll
    for (int e = 0; e < 16; ++e) p[e] = fmaf(ex[e], wi, p[e]);
}

__global__ __launch_bounds__(256) void router_kernel(
    const float* __restrict__ GL, const float* __restrict__ SL,
    float* __restrict__ out, float* __restrict__ accum)
{
    const int t = blockIdx.x * 256 + threadIdx.x;

    float p[16];
#pragma unroll
    for (int e = 0; e < 16; ++e) p[e] = 0.f;

    softmax16_acc(GL + (size_t)t * E_, ALPHA_, p);
#pragma unroll
    for (int m = 0; m < 4; ++m)
        softmax16_acc(SL + ((size_t)m * M_TOK + t) * E_, (1.f - ALPHA_) * 0.5f, p);

    const size_t NTOT = (size_t)M_TOK * E_ * CAP_;
    float* probs_out = out + 2 * NTOT + (size_t)t * E_;
#pragma unroll
    for (int e = 0; e < 16; ++e) probs_out[e] = p[e];

    float red[16];
#pragma unroll
    for (int e = 0; e < 16; ++e) red[e] = p[e];
#pragma unroll
    for (int m = 1; m < 64; m <<= 1)
#pragma unroll
        for (int e = 0; e < 16; ++e) red[e] += __shfl_xor(red[e], m);
    const int lane = threadIdx.x & 63;
#pragma unroll
    for (int e = 0; e < 16; ++e)
        if (lane == e) atomicAdd(&accum[e], red[e]);

    float tmp[16];
#pragma unroll
    for (int e = 0; e < 16; ++e) tmp[e] = p[e];
    int   bi[4];
    float bv[4];
    float s4 = 0.f;
#pragma unroll
    for (int kk = 0; kk < 4; ++kk) {
        float best = -1.f; int besti = 0;
#pragma unroll
        for (int e = 0; e < 16; ++e)
            if (tmp[e] > best) { best = tmp[e]; besti = e; }
        bi[kk] = besti; bv[kk] = best; s4 += best;
        tmp[besti] = -1.f;
    }
    const float inv = 1.f / s4;
#pragma unroll
    for (int kk = 0; kk < 4; ++kk) {
        const size_t base = ((size_t)t * E_ + bi[kk]) * CAP_;
        out[base] = 1.0f;
        out[NTOT + base] = bv[kk] * inv;
    }
}

__global__ void aux_kernel(const float* __restrict__ accum,
                           float* __restrict__ out, unsigned long long pos)
{
    if (threadIdx.x == 0 && blockIdx.x == 0) {
        float s = 0.f;
#pragma unroll
        for (int e = 0; e < 16; ++e) {
            float m = accum[e] * (1.0f / (float)M_TOK);
            s += m * logf(m * (float)E_ + 1e-9f);
        }
        out[pos] = s;
    }
}

// ---------------------------------------------------------------------------
extern "C" void kernel_launch(void* const* d_in, const int* in_sizes, int n_in,
                              void* d_out, int out_size, void* d_ws, size_t ws_size,
                              hipStream_t stream)
{
    const float* hidden = (const float*)d_in[0];
    const float* mimg   = (const float*)d_in[1];
    const float* mgen   = (const float*)d_in[2];
    const float* Wg1 = (const float*)d_in[3];
    const float* bg1 = (const float*)d_in[4];
    const float* Wg2 = (const float*)d_in[5];
    const float* bg2 = (const float*)d_in[6];
    const float* Wm1 = (const float*)d_in[7];
    const float* bm1 = (const float*)d_in[8];
    const float* Wm2 = (const float*)d_in[9];
    const float* bm2 = (const float*)d_in[10];
    const float* Ws1 = (const float*)d_in[11];  // [4,H,H2]
    const float* bs1 = (const float*)d_in[12];  // [4,H2]
    const float* Ws2 = (const float*)d_in[13];  // [4,H2,E]
    const float* bs2 = (const float*)d_in[14];  // [4,E]

    float* out = (float*)d_out;

    // workspace layout
    char* p = (char*)d_ws;
    float* accum = (float*)p;            p += 256;
    float* G1    = (float*)p;            p += (size_t)M_TOK * H_ * 4;
    float* S1    = (float*)p;            p += (size_t)4 * M_TOK * H2_ * 4;
    float* GL    = (float*)p;            p += (size_t)M_TOK * E_ * 4;
    float* SL    = (float*)p;            p += (size_t)4 * M_TOK * E_ * 4;
    _Float16* hid_h = (_Float16*)p;      p += (size_t)M_TOK * H_ * 2;
    _Float16* hid_l = (_Float16*)p;      p += (size_t)M_TOK * H_ * 2;
    _Float16* img_h = (_Float16*)p;      p += (size_t)M_TOK * H_ * 2;
    _Float16* img_l = (_Float16*)p;      p += (size_t)M_TOK * H_ * 2;
    _Float16* gen_h = (_Float16*)p;      p += (size_t)M_TOK * H_ * 2;
    _Float16* gen_l = (_Float16*)p;      p += (size_t)M_TOK * H_ * 2;
    _Float16* T1_h  = (_Float16*)p;      p += (size_t)M_TOK * H_ * 2;
    _Float16* T1_l  = (_Float16*)p;      p += (size_t)M_TOK * H_ * 2;
    _Float16* MI_h  = (_Float16*)p;      p += (size_t)M_TOK * H_ * 2;
    _Float16* MI_l  = (_Float16*)p;      p += (size_t)M_TOK * H_ * 2;
    _Float16* Wm1t_h = (_Float16*)p;     p += (size_t)H_ * H_ * 2;
    _Float16* Wm1t_l = (_Float16*)p;     p += (size_t)H_ * H_ * 2;
    _Float16* Wg1t_h = (_Float16*)p;     p += (size_t)H_ * H_ * 2;
    _Float16* Wg1t_l = (_Float16*)p;     p += (size_t)H_ * H_ * 2;
    _Float16* Wm2t_h = (_Float16*)p;     p += (size_t)H_ * H_ * 2;
    _Float16* Wm2t_l = (_Float16*)p;     p += (size_t)H_ * H_ * 2;
    _Float16* Ws1t_h = (_Float16*)p;     p += (size_t)4 * H2_ * H_ * 2;
    _Float16* Ws1t_l = (_Float16*)p;     p += (size_t)4 * H2_ * H_ * 2;

    hipMemsetAsync(d_out, 0, (size_t)out_size * sizeof(float), stream);
    hipMemsetAsync(accum, 0, 16 * sizeof(float), stream);

    const dim3 blk(256);

    // 1) activation split (hidden, image, genomic)
    APack ap;
    ap.g[0] = {hidden, hid_h, hid_l};
    ap.g[1] = {mimg,   img_h, img_l};
    ap.g[2] = {mgen,   gen_h, gen_l};
    asplit_kernel<<<dim3((M_TOK * H_) / (256 * 8), 1, 3), blk, 0, stream>>>(ap);

    // 2) weight split+transpose (scaled by 64)
    WPack wp;
    wp.g[0] = {Wm1, Wm1t_h, Wm1t_l, H_, H_};
    wp.g[1] = {Wg1, Wg1t_h, Wg1t_l, H_, H_};
    wp.g[2] = {Wm2, Wm2t_h, Wm2t_l, H_, H_};
    for (int m = 0; m < 4; ++m)
        wp.g[3 + m] = {Ws1 + (size_t)m * H_ * H2_,
                       Ws1t_h + (size_t)m * H2_ * H_,
                       Ws1t_l + (size_t)m * H2_ * H_, H_, H2_};
    wsplit_kernel<<<dim3(32, 32, 7), blk, 0, stream>>>(wp);

    // 3) batch A: input-only GEMMs
    GPack pa;
    pa.g[0] = {hid_h, hid_l, Wm1t_h, Wm1t_l, bm1, nullptr, T1_h, T1_l, H_, H_, 16, 1, 1};
    pa.g[1] = {hid_h, hid_l, Wg1t_h, Wg1t_l, bg1, G1, nullptr, nullptr, H_, H_, 16, 1, 0};
    pa.g[2] = {img_h, img_l, Ws1t_h + (size_t)0 * H2_ * H_, Ws1t_l + (size_t)0 * H2_ * H_,
               bs1 + 0 * H2_, S1 + (size_t)0 * M_TOK * H2_, nullptr, nullptr, H_, H2_, 8, 1, 0};
    pa.g[3] = {gen_h, gen_l, Ws1t_h + (size_t)1 * H2_ * H_, Ws1t_l + (size_t)1 * H2_ * H_,
               bs1 + 1 * H2_, S1 + (size_t)1 * M_TOK * H2_, nullptr, nullptr, H_, H2_, 8, 1, 0};
    gemm_mfma_kernel<<<dim3(16, M_TOK / 256, 4), blk, 0, stream>>>(pa);

    // 4) MISS = T1 @ Wm2 + bm2 (no relu), f16 h/l out
    GPack pb;
    pb.g[0] = {T1_h, T1_l, Wm2t_h, Wm2t_l, bm2, nullptr, MI_h, MI_l, H_, H_, 16, 0, 1};
    pb.g[1] = pb.g[0]; pb.g[2] = pb.g[0]; pb.g[3] = pb.g[0];
    gemm_mfma_kernel<<<dim3(16, M_TOK / 256, 1), blk, 0, stream>>>(pb);

    // 5) specialized routers on imputed modalities
    GPack pc;
    pc.g[0] = {MI_h, MI_l, Ws1t_h + (size_t)2 * H2_ * H_, Ws1t_l + (size_t)2 * H2_ * H_,
               bs1 + 2 * H2_, S1 + (size_t)2 * M_TOK * H2_, nullptr, nullptr, H_, H2_, 8, 1, 0};
    pc.g[1] = {MI_h, MI_l, Ws1t_h + (size_t)3 * H2_ * H_, Ws1t_l + (size_t)3 * H2_ * H_,
               bs1 + 3 * H2_, S1 + (size_t)3 * M_TOK * H2_, nullptr, nullptr, H_, H2_, 8, 1, 0};
    pc.g[2] = pc.g[0]; pc.g[3] = pc.g[0];
    gemm_mfma_kernel<<<dim3(8, M_TOK / 256, 2), blk, 0, stream>>>(pc);

    // 6) logit GEMMs (fp32)
    SPack sp;
    sp.g[0] = {G1, Wg2, bg2, GL, H_};
    for (int m = 0; m < 4; ++m)
        sp.g[1 + m] = {S1 + (size_t)m * M_TOK * H2_, Ws2 + (size_t)m * H2_ * E_,
                       bs2 + (size_t)m * E_, SL + (size_t)m * M_TOK * E_, H2_};
    gemm_n16_kernel<<<dim3(M_TOK / 16, 1, 5), blk, 0, stream>>>(sp);

    // 7) finalize
    router_kernel<<<M_TOK / 256, blk, 0, stream>>>(GL, SL, out, accum);
    aux_kernel<<<1, 64, 0, stream>>>(accum, out, (unsigned long long)out_size - 1);
}

// Round 6
// 737.481 us; speedup vs baseline: 1.1682x; 1.1682x over previous
//
#include <hip/hip_runtime.h>
#include <math.h>

// Problem constants (B=4, S=512, H=2048, E=16, K=4)
#define M_TOK 2048
#define H_    2048
#define H2_   1024
#define E_    16
#define CAP_  768
#define ALPHA_ 0.7f
#define WSCALE 64.0f
#define INV_WSCALE (1.0f / 64.0f)

typedef _Float16 half8 __attribute__((ext_vector_type(8)));
typedef float f32x4 __attribute__((ext_vector_type(4)));

typedef __attribute__((address_space(1))) const unsigned int* gas_ptr;
typedef __attribute__((address_space(3))) unsigned int* las_ptr;

__device__ __forceinline__ void load_lds16(const void* g, void* l) {
    __builtin_amdgcn_global_load_lds((gas_ptr)g, (las_ptr)l, 16, 0, 0);
}

// split 8 fp32 -> half8 hi + half8 lo
__device__ __forceinline__ void split8(const f32x4 a, const f32x4 b,
                                       half8* hi, half8* lo) {
#pragma unroll
    for (int i = 0; i < 4; ++i) {
        _Float16 h0 = (_Float16)a[i];
        (*hi)[i] = h0;
        (*lo)[i] = (_Float16)(a[i] - (float)h0);
        _Float16 h1 = (_Float16)b[i];
        (*hi)[i + 4] = h1;
        (*lo)[i + 4] = (_Float16)(b[i] - (float)h1);
    }
}

// ---------------------------------------------------------------------------
// Activation split: fp32 [M,K] -> f16 hi/lo [M,K]
// ---------------------------------------------------------------------------
struct ADesc { const float* A; _Float16* oh; _Float16* ol; };
struct APack { ADesc g[3]; };

__global__ __launch_bounds__(256) void asplit_kernel(APack pack)
{
    ADesc d;
    switch (blockIdx.z) {
        case 0: d = pack.g[0]; break;
        case 1: d = pack.g[1]; break;
        default: d = pack.g[2]; break;
    }
    const size_t i = ((size_t)blockIdx.x * 256 + threadIdx.x) * 8;
    f32x4 v0 = *(const f32x4*)(d.A + i);
    f32x4 v1 = *(const f32x4*)(d.A + i + 4);
    half8 h, l;
    split8(v0, v1, &h, &l);
    *(half8*)(d.oh + i) = h;
    *(half8*)(d.ol + i) = l;
}

// ---------------------------------------------------------------------------
// Weight split+transpose: W fp32 [K,N] -> Wt_h/Wt_l f16 [N,K], scaled by 64.
// ---------------------------------------------------------------------------
struct WDesc { const float* W; _Float16* oh; _Float16* ol; int K; int N; };
struct WPack { WDesc g[7]; };

__global__ __launch_bounds__(256) void wsplit_kernel(WPack pack)
{
    WDesc d;
    switch (blockIdx.z) {
        case 0: d = pack.g[0]; break;
        case 1: d = pack.g[1]; break;
        case 2: d = pack.g[2]; break;
        case 3: d = pack.g[3]; break;
        case 4: d = pack.g[4]; break;
        case 5: d = pack.g[5]; break;
        default: d = pack.g[6]; break;
    }
    const int n0 = blockIdx.y * 64;
    if (n0 >= d.N) return;
    const int k0 = blockIdx.x * 64;

    __shared__ float T[64][68];
    const int t = threadIdx.x;

    {
        const int kr = t >> 2;
        const int c0 = (t & 3) << 4;
        const float* src = d.W + (size_t)(k0 + kr) * d.N + n0 + c0;
        f32x4 v0 = *(const f32x4*)(src);
        f32x4 v1 = *(const f32x4*)(src + 4);
        f32x4 v2 = *(const f32x4*)(src + 8);
        f32x4 v3 = *(const f32x4*)(src + 12);
#pragma unroll
        for (int i = 0; i < 4; ++i) T[c0 + i][kr]      = v0[i];
#pragma unroll
        for (int i = 0; i < 4; ++i) T[c0 + 4 + i][kr]  = v1[i];
#pragma unroll
        for (int i = 0; i < 4; ++i) T[c0 + 8 + i][kr]  = v2[i];
#pragma unroll
        for (int i = 0; i < 4; ++i) T[c0 + 12 + i][kr] = v3[i];
    }
    __syncthreads();

    {
        const int n  = t >> 2;
        const int kj = (t & 3) << 4;
        half8 h0, l0, h1, l1;
        f32x4 u0 = *(const f32x4*)&T[n][kj];
        f32x4 u1 = *(const f32x4*)&T[n][kj + 4];
        f32x4 u2 = *(const f32x4*)&T[n][kj + 8];
        f32x4 u3 = *(const f32x4*)&T[n][kj + 12];
        u0 *= WSCALE; u1 *= WSCALE; u2 *= WSCALE; u3 *= WSCALE;
        split8(u0, u1, &h0, &l0);
        split8(u2, u3, &h1, &l1);
        const size_t o = (size_t)(n0 + n) * d.K + k0 + kj;
        *(half8*)(d.oh + o)     = h0;
        *(half8*)(d.oh + o + 8) = h1;
        *(half8*)(d.ol + o)     = l0;
        *(half8*)(d.ol + o + 8) = l1;
    }
}

// ---------------------------------------------------------------------------
// f16x3 MFMA GEMM, both operands pre-split f16 [rows,K].
// Block 128x128 (R4 geometry: 4 waves x 64x64, 64 AGPR acc -> 2+ blocks/CU),
// BK=32, all staging via global_load_lds, swizzled granules (0 conflicts).
// mode 0: fp32 out; mode 1: f16 hi/lo out (for chained GEMMs).
// ---------------------------------------------------------------------------
struct GDesc {
    const _Float16* Ah; const _Float16* Al;
    const _Float16* Wh; const _Float16* Wl;
    const float* bias; float* Cf; _Float16* Ch; _Float16* Cl;
    int K; int N; int ntn; int relu; int mode;
};
struct GPack { GDesc g[4]; };

__global__ __launch_bounds__(256) void gemm_mfma_kernel(GPack pack)
{
    GDesc d;
    switch (blockIdx.z) {
        case 0: d = pack.g[0]; break;
        case 1: d = pack.g[1]; break;
        case 2: d = pack.g[2]; break;
        default: d = pack.g[3]; break;
    }
    const int mt_ = blockIdx.x >> 2;
    const int nt_ = (blockIdx.y << 2) + (blockIdx.x & 3);
    if (nt_ >= d.ntn) return;
    const int bm = mt_ * 128, bn = nt_ * 128;
    const int K = d.K, N = d.N;

    // granule layout: slot g holds (row = g>>2, q = ((g&3) - (row>>1))&3);
    // fragment read of (row,q) at slot row*4 + ((q + (row>>1))&3)
    // -> every b128 access <=2-way (free). [verified 0 conflicts R4/R5]
    __shared__ _Float16 Ah_s[128 * 32];   // 8 KB each, 32 KB total
    __shared__ _Float16 Al_s[128 * 32];
    __shared__ _Float16 Bh_s[128 * 32];
    __shared__ _Float16 Bl_s[128 * 32];

    const int tid  = threadIdx.x;
    const int lane = tid & 63;
    const int wave = tid >> 6;
    const int wm = wave >> 1, wn = wave & 1;

    // staging map (2 issues per thread per array; 512 granules)
    int s_row[2], s_q[2];
#pragma unroll
    for (int is = 0; is < 2; ++is) {
        const int g = tid + (is << 8);
        s_row[is] = g >> 2;
        s_q[is]   = ((g & 3) - (s_row[is] >> 1)) & 3;
    }

    // fragment read offsets (mt/nt step of 16 rows keeps swizzle class)
    const int am0  = wm * 64 + (lane & 15);
    const int aoff = (am0 * 4 + (((lane >> 4) + (am0 >> 1)) & 3)) * 8;
    const int bn0  = wn * 64 + (lane & 15);
    const int boff = (bn0 * 4 + (((lane >> 4) + (bn0 >> 1)) & 3)) * 8;

    f32x4 acc[4][4];
#pragma unroll
    for (int i = 0; i < 4; ++i)
#pragma unroll
        for (int j = 0; j < 4; ++j) acc[i][j] = (f32x4)0.f;

    for (int k0 = 0; k0 < K; k0 += 32) {
        if (k0) __syncthreads();   // prev tile fully consumed

#pragma unroll
        for (int is = 0; is < 2; ++is) {
            const size_t ga = (size_t)(bm + s_row[is]) * K + k0 + s_q[is] * 8;
            const size_t gb = (size_t)(bn + s_row[is]) * K + k0 + s_q[is] * 8;
            const size_t lo = (size_t)(tid + (is << 8)) * 8;
            load_lds16(d.Ah + ga, &Ah_s[lo]);
            load_lds16(d.Al + ga, &Al_s[lo]);
            load_lds16(d.Wh + gb, &Bh_s[lo]);
            load_lds16(d.Wl + gb, &Bl_s[lo]);
        }

        __syncthreads();   // drains DMA (vmcnt) before reads

        half8 fAh[4], fAl[4];
#pragma unroll
        for (int mt = 0; mt < 4; ++mt) {
            fAh[mt] = *(const half8*)&Ah_s[aoff + mt * 512];
            fAl[mt] = *(const half8*)&Al_s[aoff + mt * 512];
        }
#pragma unroll
        for (int nt = 0; nt < 4; ++nt) {
            half8 fBh = *(const half8*)&Bh_s[boff + nt * 512];
            half8 fBl = *(const half8*)&Bl_s[boff + nt * 512];
#pragma unroll
            for (int mt = 0; mt < 4; ++mt) {
                acc[mt][nt] = __builtin_amdgcn_mfma_f32_16x16x32_f16(
                    fAh[mt], fBh, acc[mt][nt], 0, 0, 0);
                acc[mt][nt] = __builtin_amdgcn_mfma_f32_16x16x32_f16(
                    fAh[mt], fBl, acc[mt][nt], 0, 0, 0);
                acc[mt][nt] = __builtin_amdgcn_mfma_f32_16x16x32_f16(
                    fAl[mt], fBh, acc[mt][nt], 0, 0, 0);
            }
        }
    }

    // epilogue: C/D layout col=lane&15, row=(lane>>4)*4+reg
    const int erow0 = bm + wm * 64 + ((lane >> 4) << 2);
    const int ecol0 = bn + wn * 64 + (lane & 15);
#pragma unroll
    for (int nt = 0; nt < 4; ++nt) {
        const int col = ecol0 + nt * 16;
        const float bb = d.bias[col];
#pragma unroll
        for (int mt = 0; mt < 4; ++mt) {
            f32x4 a = acc[mt][nt];
#pragma unroll
            for (int r = 0; r < 4; ++r) {
                float v = a[r] * INV_WSCALE + bb;
                if (d.relu) v = fmaxf(v, 0.f);
                const size_t o = (size_t)(erow0 + mt * 16 + r) * N + col;
                if (d.mode == 0) {
                    d.Cf[o] = v;
                } else {
                    _Float16 h = (_Float16)v;
                    d.Ch[o] = h;
                    d.Cl[o] = (_Float16)(v - (float)h);
                }
            }
        }
    }
}

// ---------------------------------------------------------------------------
// Batched skinny GEMM: C[M,16] = A[M,K] @ W[K,16] + bias[16]   (fp32)
// ---------------------------------------------------------------------------
struct SDesc { const float* A; const float* W; const float* bias; float* C; int K; };
struct SPack { SDesc g[5]; };

__global__ __launch_bounds__(256) void gemm_n16_kernel(SPack pack)
{
    SDesc d;
    switch (blockIdx.z) {
        case 0: d = pack.g[0]; break;
        case 1: d = pack.g[1]; break;
        case 2: d = pack.g[2]; break;
        case 3: d = pack.g[3]; break;
        default: d = pack.g[4]; break;
    }
    __shared__ float As[16][68];
    __shared__ float Ws[64][16];

    const int tid = threadIdx.x;
    const int e = tid & 15;
    const int r = tid >> 4;
    const int row0 = blockIdx.x * 16;

    const int lr  = tid >> 4;
    const int lk4 = (tid & 15) << 2;
    const int wk  = tid >> 2;
    const int we4 = (tid & 3) << 2;

    const int K = d.K;
    float acc = 0.f;
    for (int k0 = 0; k0 < K; k0 += 64) {
        float4 av = *(const float4*)&d.A[(size_t)(row0 + lr) * K + k0 + lk4];
        float4 wv = *(const float4*)&d.W[(size_t)(k0 + wk) * E_ + we4];
        if (k0) __syncthreads();
        *(float4*)&As[lr][lk4] = av;
        *(float4*)&Ws[wk][we4] = wv;
        __syncthreads();
#pragma unroll
        for (int kk = 0; kk < 64; kk += 4) {
            float4 a = *(const float4*)&As[r][kk];
            acc = fmaf(a.x, Ws[kk + 0][e], acc);
            acc = fmaf(a.y, Ws[kk + 1][e], acc);
            acc = fmaf(a.z, Ws[kk + 2][e], acc);
            acc = fmaf(a.w, Ws[kk + 3][e], acc);
        }
    }
    d.C[(size_t)(row0 + r) * E_ + e] = acc + d.bias[e];
}

// ---------------------------------------------------------------------------
// Router finalize
// ---------------------------------------------------------------------------
__device__ __forceinline__ void softmax16_acc(const float* __restrict__ lg,
                                              float w, float* __restrict__ p)
{
    float mx = lg[0];
#pragma unroll
    for (int e = 1; e < 16; ++e) mx = fmaxf(mx, lg[e]);
    float ex[16];
    float s = 0.f;
#pragma unroll
    for (int e = 0; e < 16; ++e) { ex[e] = expf(lg[e] - mx); s += ex[e]; }
    const float wi = w / s;
#pragma unroll
    for (int e = 0; e < 16; ++e) p[e] = fmaf(ex[e], wi, p[e]);
}

__global__ __launch_bounds__(256) void router_kernel(
    const float* __restrict__ GL, const float* __restrict__ SL,
    float* __restrict__ out, float* __restrict__ accum)
{
    const int t = blockIdx.x * 256 + threadIdx.x;

    float p[16];
#pragma unroll
    for (int e = 0; e < 16; ++e) p[e] = 0.f;

    softmax16_acc(GL + (size_t)t * E_, ALPHA_, p);
#pragma unroll
    for (int m = 0; m < 4; ++m)
        softmax16_acc(SL + ((size_t)m * M_TOK + t) * E_, (1.f - ALPHA_) * 0.5f, p);

    const size_t NTOT = (size_t)M_TOK * E_ * CAP_;
    float* probs_out = out + 2 * NTOT + (size_t)t * E_;
#pragma unroll
    for (int e = 0; e < 16; ++e) probs_out[e] = p[e];

    float red[16];
#pragma unroll
    for (int e = 0; e < 16; ++e) red[e] = p[e];
#pragma unroll
    for (int m = 1; m < 64; m <<= 1)
#pragma unroll
        for (int e = 0; e < 16; ++e) red[e] += __shfl_xor(red[e], m);
    const int lane = threadIdx.x & 63;
#pragma unroll
    for (int e = 0; e < 16; ++e)
        if (lane == e) atomicAdd(&accum[e], red[e]);

    float tmp[16];
#pragma unroll
    for (int e = 0; e < 16; ++e) tmp[e] = p[e];
    int   bi[4];
    float bv[4];
    float s4 = 0.f;
#pragma unroll
    for (int kk = 0; kk < 4; ++kk) {
        float best = -1.f; int besti = 0;
#pragma unroll
        for (int e = 0; e < 16; ++e)
            if (tmp[e] > best) { best = tmp[e]; besti = e; }
        bi[kk] = besti; bv[kk] = best; s4 += best;
        tmp[besti] = -1.f;
    }
    const float inv = 1.f / s4;
#pragma unroll
    for (int kk = 0; kk < 4; ++kk) {
        const size_t base = ((size_t)t * E_ + bi[kk]) * CAP_;
        out[base] = 1.0f;
        out[NTOT + base] = bv[kk] * inv;
    }
}

__global__ void aux_kernel(const float* __restrict__ accum,
                           float* __restrict__ out, unsigned long long pos)
{
    if (threadIdx.x == 0 && blockIdx.x == 0) {
        float s = 0.f;
#pragma unroll
        for (int e = 0; e < 16; ++e) {
            float m = accum[e] * (1.0f / (float)M_TOK);
            s += m * logf(m * (float)E_ + 1e-9f);
        }
        out[pos] = s;
    }
}

// ---------------------------------------------------------------------------
extern "C" void kernel_launch(void* const* d_in, const int* in_sizes, int n_in,
                              void* d_out, int out_size, void* d_ws, size_t ws_size,
                              hipStream_t stream)
{
    const float* hidden = (const float*)d_in[0];
    const float* mimg   = (const float*)d_in[1];
    const float* mgen   = (const float*)d_in[2];
    const float* Wg1 = (const float*)d_in[3];
    const float* bg1 = (const float*)d_in[4];
    const float* Wg2 = (const float*)d_in[5];
    const float* bg2 = (const float*)d_in[6];
    const float* Wm1 = (const float*)d_in[7];
    const float* bm1 = (const float*)d_in[8];
    const float* Wm2 = (const float*)d_in[9];
    const float* bm2 = (const float*)d_in[10];
    const float* Ws1 = (const float*)d_in[11];  // [4,H,H2]
    const float* bs1 = (const float*)d_in[12];  // [4,H2]
    const float* Ws2 = (const float*)d_in[13];  // [4,H2,E]
    const float* bs2 = (const float*)d_in[14];  // [4,E]

    float* out = (float*)d_out;

    // workspace layout
    char* p = (char*)d_ws;
    float* accum = (float*)p;            p += 256;
    float* G1    = (float*)p;            p += (size_t)M_TOK * H_ * 4;
    float* S1    = (float*)p;            p += (size_t)4 * M_TOK * H2_ * 4;
    float* GL    = (float*)p;            p += (size_t)M_TOK * E_ * 4;
    float* SL    = (float*)p;            p += (size_t)4 * M_TOK * E_ * 4;
    _Float16* hid_h = (_Float16*)p;      p += (size_t)M_TOK * H_ * 2;
    _Float16* hid_l = (_Float16*)p;      p += (size_t)M_TOK * H_ * 2;
    _Float16* img_h = (_Float16*)p;      p += (size_t)M_TOK * H_ * 2;
    _Float16* img_l = (_Float16*)p;      p += (size_t)M_TOK * H_ * 2;
    _Float16* gen_h = (_Float16*)p;      p += (size_t)M_TOK * H_ * 2;
    _Float16* gen_l = (_Float16*)p;      p += (size_t)M_TOK * H_ * 2;
    _Float16* T1_h  = (_Float16*)p;      p += (size_t)M_TOK * H_ * 2;
    _Float16* T1_l  = (_Float16*)p;      p += (size_t)M_TOK * H_ * 2;
    _Float16* MI_h  = (_Float16*)p;      p += (size_t)M_TOK * H_ * 2;
    _Float16* MI_l  = (_Float16*)p;      p += (size_t)M_TOK * H_ * 2;
    _Float16* Wm1t_h = (_Float16*)p;     p += (size_t)H_ * H_ * 2;
    _Float16* Wm1t_l = (_Float16*)p;     p += (size_t)H_ * H_ * 2;
    _Float16* Wg1t_h = (_Float16*)p;     p += (size_t)H_ * H_ * 2;
    _Float16* Wg1t_l = (_Float16*)p;     p += (size_t)H_ * H_ * 2;
    _Float16* Wm2t_h = (_Float16*)p;     p += (size_t)H_ * H_ * 2;
    _Float16* Wm2t_l = (_Float16*)p;     p += (size_t)H_ * H_ * 2;
    _Float16* Ws1t_h = (_Float16*)p;     p += (size_t)4 * H2_ * H_ * 2;
    _Float16* Ws1t_l = (_Float16*)p;     p += (size_t)4 * H2_ * H_ * 2;

    hipMemsetAsync(d_out, 0, (size_t)out_size * sizeof(float), stream);
    hipMemsetAsync(accum, 0, 16 * sizeof(float), stream);

    const dim3 blk(256);

    // 1) activation split (hidden, image, genomic)
    APack ap;
    ap.g[0] = {hidden, hid_h, hid_l};
    ap.g[1] = {mimg,   img_h, img_l};
    ap.g[2] = {mgen,   gen_h, gen_l};
    asplit_kernel<<<dim3((M_TOK * H_) / (256 * 8), 1, 3), blk, 0, stream>>>(ap);

    // 2) weight split+transpose (scaled by 64)
    WPack wp;
    wp.g[0] = {Wm1, Wm1t_h, Wm1t_l, H_, H_};
    wp.g[1] = {Wg1, Wg1t_h, Wg1t_l, H_, H_};
    wp.g[2] = {Wm2, Wm2t_h, Wm2t_l, H_, H_};
    for (int m = 0; m < 4; ++m)
        wp.g[3 + m] = {Ws1 + (size_t)m * H_ * H2_,
                       Ws1t_h + (size_t)m * H2_ * H_,
                       Ws1t_l + (size_t)m * H2_ * H_, H_, H2_};
    wsplit_kernel<<<dim3(32, 32, 7), blk, 0, stream>>>(wp);

    // 3) batch A: input-only GEMMs (128x128 tiles, R4 geometry)
    GPack pa;
    pa.g[0] = {hid_h, hid_l, Wm1t_h, Wm1t_l, bm1, nullptr, T1_h, T1_l, H_, H_, 16, 1, 1};
    pa.g[1] = {hid_h, hid_l, Wg1t_h, Wg1t_l, bg1, G1, nullptr, nullptr, H_, H_, 16, 1, 0};
    pa.g[2] = {img_h, img_l, Ws1t_h + (size_t)0 * H2_ * H_, Ws1t_l + (size_t)0 * H2_ * H_,
               bs1 + 0 * H2_, S1 + (size_t)0 * M_TOK * H2_, nullptr, nullptr, H_, H2_, 8, 1, 0};
    pa.g[3] = {gen_h, gen_l, Ws1t_h + (size_t)1 * H2_ * H_, Ws1t_l + (size_t)1 * H2_ * H_,
               bs1 + 1 * H2_, S1 + (size_t)1 * M_TOK * H2_, nullptr, nullptr, H_, H2_, 8, 1, 0};
    gemm_mfma_kernel<<<dim3(64, 4, 4), blk, 0, stream>>>(pa);

    // 4) MISS = T1 @ Wm2 + bm2 (no relu), f16 h/l out
    GPack pb;
    pb.g[0] = {T1_h, T1_l, Wm2t_h, Wm2t_l, bm2, nullptr, MI_h, MI_l, H_, H_, 16, 0, 1};
    pb.g[1] = pb.g[0]; pb.g[2] = pb.g[0]; pb.g[3] = pb.g[0];
    gemm_mfma_kernel<<<dim3(64, 4, 1), blk, 0, stream>>>(pb);

    // 5) specialized routers on imputed modalities
    GPack pc;
    pc.g[0] = {MI_h, MI_l, Ws1t_h + (size_t)2 * H2_ * H_, Ws1t_l + (size_t)2 * H2_ * H_,
               bs1 + 2 * H2_, S1 + (size_t)2 * M_TOK * H2_, nullptr, nullptr, H_, H2_, 8, 1, 0};
    pc.g[1] = {MI_h, MI_l, Ws1t_h + (size_t)3 * H2_ * H_, Ws1t_l + (size_t)3 * H2_ * H_,
               bs1 + 3 * H2_, S1 + (size_t)3 * M_TOK * H2_, nullptr, nullptr, H_, H2_, 8, 1, 0};
    pc.g[2] = pc.g[0]; pc.g[3] = pc.g[0];
    gemm_mfma_kernel<<<dim3(64, 2, 2), blk, 0, stream>>>(pc);

    // 6) logit GEMMs (fp32)
    SPack sp;
    sp.g[0] = {G1, Wg2, bg2, GL, H_};
    for (int m = 0; m < 4; ++m)
        sp.g[1 + m] = {S1 + (size_t)m * M_TOK * H2_, Ws2 + (size_t)m * H2_ * E_,
                       bs2 + (size_t)m * E_, SL + (size_t)m * M_TOK * E_, H2_};
    gemm_n16_kernel<<<dim3(M_TOK / 16, 1, 5), blk, 0, stream>>>(sp);

    // 7) finalize
    router_kernel<<<M_TOK / 256, blk, 0, stream>>>(GL, SL, out, accum);
    aux_kernel<<<1, 64, 0, stream>>>(accum, out, (unsigned long long)out_size - 1);
}

// Round 7
// 734.380 us; speedup vs baseline: 1.1731x; 1.0042x over previous
//
#include <hip/hip_runtime.h>
#include <math.h>

// Problem constants (B=4, S=512, H=2048, E=16, K=4)
#define M_TOK 2048
#define H_    2048
#define H2_   1024
#define E_    16
#define CAP_  768
#define ALPHA_ 0.7f
#define WSCALE 64.0f
#define INV_WSCALE (1.0f / 64.0f)

typedef _Float16 half8 __attribute__((ext_vector_type(8)));
typedef float f32x4 __attribute__((ext_vector_type(4)));

typedef __attribute__((address_space(1))) const unsigned int* gas_ptr;
typedef __attribute__((address_space(3))) unsigned int* las_ptr;

__device__ __forceinline__ void load_lds16(const void* g, void* l) {
    __builtin_amdgcn_global_load_lds((gas_ptr)g, (las_ptr)l, 16, 0, 0);
}

// split 8 fp32 -> half8 hi + half8 lo
__device__ __forceinline__ void split8(const f32x4 a, const f32x4 b,
                                       half8* hi, half8* lo) {
#pragma unroll
    for (int i = 0; i < 4; ++i) {
        _Float16 h0 = (_Float16)a[i];
        (*hi)[i] = h0;
        (*lo)[i] = (_Float16)(a[i] - (float)h0);
        _Float16 h1 = (_Float16)b[i];
        (*hi)[i + 4] = h1;
        (*lo)[i + 4] = (_Float16)(b[i] - (float)h1);
    }
}

// ---------------------------------------------------------------------------
// Activation split: fp32 [M,K] -> f16 hi/lo [M,K]
// ---------------------------------------------------------------------------
struct ADesc { const float* A; _Float16* oh; _Float16* ol; };
struct APack { ADesc g[3]; };

__global__ __launch_bounds__(256) void asplit_kernel(APack pack)
{
    ADesc d;
    switch (blockIdx.z) {
        case 0: d = pack.g[0]; break;
        case 1: d = pack.g[1]; break;
        default: d = pack.g[2]; break;
    }
    const size_t i = ((size_t)blockIdx.x * 256 + threadIdx.x) * 8;
    f32x4 v0 = *(const f32x4*)(d.A + i);
    f32x4 v1 = *(const f32x4*)(d.A + i + 4);
    half8 h, l;
    split8(v0, v1, &h, &l);
    *(half8*)(d.oh + i) = h;
    *(half8*)(d.ol + i) = l;
}

// ---------------------------------------------------------------------------
// Weight split+transpose: W fp32 [K,N] -> Wt_h/Wt_l f16 [N,K], scaled by 64.
// ---------------------------------------------------------------------------
struct WDesc { const float* W; _Float16* oh; _Float16* ol; int K; int N; };
struct WPack { WDesc g[7]; };

__global__ __launch_bounds__(256) void wsplit_kernel(WPack pack)
{
    WDesc d;
    switch (blockIdx.z) {
        case 0: d = pack.g[0]; break;
        case 1: d = pack.g[1]; break;
        case 2: d = pack.g[2]; break;
        case 3: d = pack.g[3]; break;
        case 4: d = pack.g[4]; break;
        case 5: d = pack.g[5]; break;
        default: d = pack.g[6]; break;
    }
    const int n0 = blockIdx.y * 64;
    if (n0 >= d.N) return;
    const int k0 = blockIdx.x * 64;

    __shared__ float T[64][68];
    const int t = threadIdx.x;

    {
        const int kr = t >> 2;
        const int c0 = (t & 3) << 4;
        const float* src = d.W + (size_t)(k0 + kr) * d.N + n0 + c0;
        f32x4 v0 = *(const f32x4*)(src);
        f32x4 v1 = *(const f32x4*)(src + 4);
        f32x4 v2 = *(const f32x4*)(src + 8);
        f32x4 v3 = *(const f32x4*)(src + 12);
#pragma unroll
        for (int i = 0; i < 4; ++i) T[c0 + i][kr]      = v0[i];
#pragma unroll
        for (int i = 0; i < 4; ++i) T[c0 + 4 + i][kr]  = v1[i];
#pragma unroll
        for (int i = 0; i < 4; ++i) T[c0 + 8 + i][kr]  = v2[i];
#pragma unroll
        for (int i = 0; i < 4; ++i) T[c0 + 12 + i][kr] = v3[i];
    }
    __syncthreads();

    {
        const int n  = t >> 2;
        const int kj = (t & 3) << 4;
        half8 h0, l0, h1, l1;
        f32x4 u0 = *(const f32x4*)&T[n][kj];
        f32x4 u1 = *(const f32x4*)&T[n][kj + 4];
        f32x4 u2 = *(const f32x4*)&T[n][kj + 8];
        f32x4 u3 = *(const f32x4*)&T[n][kj + 12];
        u0 *= WSCALE; u1 *= WSCALE; u2 *= WSCALE; u3 *= WSCALE;
        split8(u0, u1, &h0, &l0);
        split8(u2, u3, &h1, &l1);
        const size_t o = (size_t)(n0 + n) * d.K + k0 + kj;
        *(half8*)(d.oh + o)     = h0;
        *(half8*)(d.oh + o + 8) = h1;
        *(half8*)(d.ol + o)     = l0;
        *(half8*)(d.ol + o + 8) = l1;
    }
}

// ---------------------------------------------------------------------------
// f16x3 MFMA GEMM, both operands pre-split f16 [rows,K].
// Block 128x128, 4 waves x 64x64, BK=32. DOUBLE-BUFFERED LDS (64 KB) with
// raw s_barrier + s_waitcnt vmcnt(8): next tile's 8 DMAs stay in flight
// across the barrier (AITER-style), so DMA latency overlaps the MFMA phase.
// mode 0: fp32 out; mode 1: f16 hi/lo out (for chained GEMMs).
// ---------------------------------------------------------------------------
struct GDesc {
    const _Float16* Ah; const _Float16* Al;
    const _Float16* Wh; const _Float16* Wl;
    const float* bias; float* Cf; _Float16* Ch; _Float16* Cl;
    int K; int N; int ntn; int relu; int mode;
};
struct GPack { GDesc g[4]; };

__global__ __launch_bounds__(256) void gemm_mfma_kernel(GPack pack)
{
    GDesc d;
    switch (blockIdx.z) {
        case 0: d = pack.g[0]; break;
        case 1: d = pack.g[1]; break;
        case 2: d = pack.g[2]; break;
        default: d = pack.g[3]; break;
    }
    const int mt_ = blockIdx.x >> 2;
    const int nt_ = (blockIdx.y << 2) + (blockIdx.x & 3);
    if (nt_ >= d.ntn) return;
    const int bm = mt_ * 128, bn = nt_ * 128;
    const int K = d.K, N = d.N;

    // granule layout: slot g holds (row = g>>2, q = ((g&3) - (row>>1))&3);
    // fragment read of (row,q) at slot row*4 + ((q + (row>>1))&3)
    // -> every b128 access <=2-way (free). [verified 0 conflicts R4-R6]
    __shared__ _Float16 Ah_s[2][128 * 32];   // 8 KB x 2
    __shared__ _Float16 Al_s[2][128 * 32];
    __shared__ _Float16 Bh_s[2][128 * 32];
    __shared__ _Float16 Bl_s[2][128 * 32];

    const int tid  = threadIdx.x;
    const int lane = tid & 63;
    const int wave = tid >> 6;
    const int wm = wave >> 1, wn = wave & 1;

    // staging map (2 issues per thread per array; 512 granules)
    size_t a_goff[2], b_goff[2];
    int    s_lo[2];
#pragma unroll
    for (int is = 0; is < 2; ++is) {
        const int g = tid + (is << 8);
        const int row = g >> 2;
        const int q = ((g & 3) - (row >> 1)) & 3;
        a_goff[is] = (size_t)(bm + row) * K + q * 8;
        b_goff[is] = (size_t)(bn + row) * K + q * 8;
        s_lo[is]   = g * 8;
    }

    // fragment read offsets (mt/nt step of 16 rows keeps swizzle class)
    const int am0  = wm * 64 + (lane & 15);
    const int aoff = (am0 * 4 + (((lane >> 4) + (am0 >> 1)) & 3)) * 8;
    const int bn0  = wn * 64 + (lane & 15);
    const int boff = (bn0 * 4 + (((lane >> 4) + (bn0 >> 1)) & 3)) * 8;

    f32x4 acc[4][4];
#pragma unroll
    for (int i = 0; i < 4; ++i)
#pragma unroll
        for (int j = 0; j < 4; ++j) acc[i][j] = (f32x4)0.f;

    // 8 DMA issues per tile per thread (4 arrays x 2)
    auto issue_tile = [&](int k0, int c) {
#pragma unroll
        for (int is = 0; is < 2; ++is) {
            load_lds16(d.Ah + a_goff[is] + k0, &Ah_s[c][s_lo[is]]);
            load_lds16(d.Al + a_goff[is] + k0, &Al_s[c][s_lo[is]]);
            load_lds16(d.Wh + b_goff[is] + k0, &Bh_s[c][s_lo[is]]);
            load_lds16(d.Wl + b_goff[is] + k0, &Bl_s[c][s_lo[is]]);
        }
    };

    issue_tile(0, 0);

    const int niter = K >> 5;
    for (int it = 0; it < niter; ++it) {
        const int cur = it & 1;

        // #1: all waves done reading buf[cur^1] (raw barrier, no vmcnt drain)
        asm volatile("" ::: "memory");
        __builtin_amdgcn_s_barrier();

        if (it + 1 < niter) {
            issue_tile((it + 1) << 5, cur ^ 1);
            // wait for tile `it` (8 newest DMAs = tile it+1 stay in flight)
            asm volatile("s_waitcnt vmcnt(8)" ::: "memory");
        } else {
            asm volatile("s_waitcnt vmcnt(0)" ::: "memory");
        }

        // #2: tile `it` visible to all waves
        __builtin_amdgcn_s_barrier();
        asm volatile("" ::: "memory");

        half8 fAh[4], fAl[4];
#pragma unroll
        for (int mt = 0; mt < 4; ++mt) {
            fAh[mt] = *(const half8*)&Ah_s[cur][aoff + mt * 512];
            fAl[mt] = *(const half8*)&Al_s[cur][aoff + mt * 512];
        }
#pragma unroll
        for (int nt = 0; nt < 4; ++nt) {
            half8 fBh = *(const half8*)&Bh_s[cur][boff + nt * 512];
            half8 fBl = *(const half8*)&Bl_s[cur][boff + nt * 512];
#pragma unroll
            for (int mt = 0; mt < 4; ++mt) {
                acc[mt][nt] = __builtin_amdgcn_mfma_f32_16x16x32_f16(
                    fAh[mt], fBh, acc[mt][nt], 0, 0, 0);
                acc[mt][nt] = __builtin_amdgcn_mfma_f32_16x16x32_f16(
                    fAh[mt], fBl, acc[mt][nt], 0, 0, 0);
                acc[mt][nt] = __builtin_amdgcn_mfma_f32_16x16x32_f16(
                    fAl[mt], fBh, acc[mt][nt], 0, 0, 0);
            }
        }
    }

    // epilogue: C/D layout col=lane&15, row=(lane>>4)*4+reg
    const int erow0 = bm + wm * 64 + ((lane >> 4) << 2);
    const int ecol0 = bn + wn * 64 + (lane & 15);
#pragma unroll
    for (int nt = 0; nt < 4; ++nt) {
        const int col = ecol0 + nt * 16;
        const float bb = d.bias[col];
#pragma unroll
        for (int mt = 0; mt < 4; ++mt) {
            f32x4 a = acc[mt][nt];
#pragma unroll
            for (int r = 0; r < 4; ++r) {
                float v = a[r] * INV_WSCALE + bb;
                if (d.relu) v = fmaxf(v, 0.f);
                const size_t o = (size_t)(erow0 + mt * 16 + r) * N + col;
                if (d.mode == 0) {
                    d.Cf[o] = v;
                } else {
                    _Float16 h = (_Float16)v;
                    d.Ch[o] = h;
                    d.Cl[o] = (_Float16)(v - (float)h);
                }
            }
        }
    }
}

// ---------------------------------------------------------------------------
// Batched skinny GEMM: C[M,16] = A[M,K] @ W[K,16] + bias[16]   (fp32)
// ---------------------------------------------------------------------------
struct SDesc { const float* A; const float* W; const float* bias; float* C; int K; };
struct SPack { SDesc g[5]; };

__global__ __launch_bounds__(256) void gemm_n16_kernel(SPack pack)
{
    SDesc d;
    switch (blockIdx.z) {
        case 0: d = pack.g[0]; break;
        case 1: d = pack.g[1]; break;
        case 2: d = pack.g[2]; break;
        case 3: d = pack.g[3]; break;
        default: d = pack.g[4]; break;
    }
    __shared__ float As[16][68];
    __shared__ float Ws[64][16];

    const int tid = threadIdx.x;
    const int e = tid & 15;
    const int r = tid >> 4;
    const int row0 = blockIdx.x * 16;

    const int lr  = tid >> 4;
    const int lk4 = (tid & 15) << 2;
    const int wk  = tid >> 2;
    const int we4 = (tid & 3) << 2;

    const int K = d.K;
    float acc = 0.f;
    for (int k0 = 0; k0 < K; k0 += 64) {
        float4 av = *(const float4*)&d.A[(size_t)(row0 + lr) * K + k0 + lk4];
        float4 wv = *(const float4*)&d.W[(size_t)(k0 + wk) * E_ + we4];
        if (k0) __syncthreads();
        *(float4*)&As[lr][lk4] = av;
        *(float4*)&Ws[wk][we4] = wv;
        __syncthreads();
#pragma unroll
        for (int kk = 0; kk < 64; kk += 4) {
            float4 a = *(const float4*)&As[r][kk];
            acc = fmaf(a.x, Ws[kk + 0][e], acc);
            acc = fmaf(a.y, Ws[kk + 1][e], acc);
            acc = fmaf(a.z, Ws[kk + 2][e], acc);
            acc = fmaf(a.w, Ws[kk + 3][e], acc);
        }
    }
    d.C[(size_t)(row0 + r) * E_ + e] = acc + d.bias[e];
}

// ---------------------------------------------------------------------------
// Router finalize
// ---------------------------------------------------------------------------
__device__ __forceinline__ void softmax16_acc(const float* __restrict__ lg,
                                              float w, float* __restrict__ p)
{
    float mx = lg[0];
#pragma unroll
    for (int e = 1; e < 16; ++e) mx = fmaxf(mx, lg[e]);
    float ex[16];
    float s = 0.f;
#pragma unroll
    for (int e = 0; e < 16; ++e) { ex[e] = expf(lg[e] - mx); s += ex[e]; }
    const float wi = w / s;
#pragma unroll
    for (int e = 0; e < 16; ++e) p[e] = fmaf(ex[e], wi, p[e]);
}

__global__ __launch_bounds__(256) void router_kernel(
    const float* __restrict__ GL, const float* __restrict__ SL,
    float* __restrict__ out, float* __restrict__ accum)
{
    const int t = blockIdx.x * 256 + threadIdx.x;

    float p[16];
#pragma unroll
    for (int e = 0; e < 16; ++e) p[e] = 0.f;

    softmax16_acc(GL + (size_t)t * E_, ALPHA_, p);
#pragma unroll
    for (int m = 0; m < 4; ++m)
        softmax16_acc(SL + ((size_t)m * M_TOK + t) * E_, (1.f - ALPHA_) * 0.5f, p);

    const size_t NTOT = (size_t)M_TOK * E_ * CAP_;
    float* probs_out = out + 2 * NTOT + (size_t)t * E_;
#pragma unroll
    for (int e = 0; e < 16; ++e) probs_out[e] = p[e];

    float red[16];
#pragma unroll
    for (int e = 0; e < 16; ++e) red[e] = p[e];
#pragma unroll
    for (int m = 1; m < 64; m <<= 1)
#pragma unroll
        for (int e = 0; e < 16; ++e) red[e] += __shfl_xor(red[e], m);
    const int lane = threadIdx.x & 63;
#pragma unroll
    for (int e = 0; e < 16; ++e)
        if (lane == e) atomicAdd(&accum[e], red[e]);

    float tmp[16];
#pragma unroll
    for (int e = 0; e < 16; ++e) tmp[e] = p[e];
    int   bi[4];
    float bv[4];
    float s4 = 0.f;
#pragma unroll
    for (int kk = 0; kk < 4; ++kk) {
        float best = -1.f; int besti = 0;
#pragma unroll
        for (int e = 0; e < 16; ++e)
            if (tmp[e] > best) { best = tmp[e]; besti = e; }
        bi[kk] = besti; bv[kk] = best; s4 += best;
        tmp[besti] = -1.f;
    }
    const float inv = 1.f / s4;
#pragma unroll
    for (int kk = 0; kk < 4; ++kk) {
        const size_t base = ((size_t)t * E_ + bi[kk]) * CAP_;
        out[base] = 1.0f;
        out[NTOT + base] = bv[kk] * inv;
    }
}

__global__ void aux_kernel(const float* __restrict__ accum,
                           float* __restrict__ out, unsigned long long pos)
{
    if (threadIdx.x == 0 && blockIdx.x == 0) {
        float s = 0.f;
#pragma unroll
        for (int e = 0; e < 16; ++e) {
            float m = accum[e] * (1.0f / (float)M_TOK);
            s += m * logf(m * (float)E_ + 1e-9f);
        }
        out[pos] = s;
    }
}

// ---------------------------------------------------------------------------
extern "C" void kernel_launch(void* const* d_in, const int* in_sizes, int n_in,
                              void* d_out, int out_size, void* d_ws, size_t ws_size,
                              hipStream_t stream)
{
    const float* hidden = (const float*)d_in[0];
    const float* mimg   = (const float*)d_in[1];
    const float* mgen   = (const float*)d_in[2];
    const float* Wg1 = (const float*)d_in[3];
    const float* bg1 = (const float*)d_in[4];
    const float* Wg2 = (const float*)d_in[5];
    const float* bg2 = (const float*)d_in[6];
    const float* Wm1 = (const float*)d_in[7];
    const float* bm1 = (const float*)d_in[8];
    const float* Wm2 = (const float*)d_in[9];
    const float* bm2 = (const float*)d_in[10];
    const float* Ws1 = (const float*)d_in[11];  // [4,H,H2]
    const float* bs1 = (const float*)d_in[12];  // [4,H2]
    const float* Ws2 = (const float*)d_in[13];  // [4,H2,E]
    const float* bs2 = (const float*)d_in[14];  // [4,E]

    float* out = (float*)d_out;

    // workspace layout
    char* p = (char*)d_ws;
    float* accum = (float*)p;            p += 256;
    float* G1    = (float*)p;            p += (size_t)M_TOK * H_ * 4;
    float* S1    = (float*)p;            p += (size_t)4 * M_TOK * H2_ * 4;
    float* GL    = (float*)p;            p += (size_t)M_TOK * E_ * 4;
    float* SL    = (float*)p;            p += (size_t)4 * M_TOK * E_ * 4;
    _Float16* hid_h = (_Float16*)p;      p += (size_t)M_TOK * H_ * 2;
    _Float16* hid_l = (_Float16*)p;      p += (size_t)M_TOK * H_ * 2;
    _Float16* img_h = (_Float16*)p;      p += (size_t)M_TOK * H_ * 2;
    _Float16* img_l = (_Float16*)p;      p += (size_t)M_TOK * H_ * 2;
    _Float16* gen_h = (_Float16*)p;      p += (size_t)M_TOK * H_ * 2;
    _Float16* gen_l = (_Float16*)p;      p += (size_t)M_TOK * H_ * 2;
    _Float16* T1_h  = (_Float16*)p;      p += (size_t)M_TOK * H_ * 2;
    _Float16* T1_l  = (_Float16*)p;      p += (size_t)M_TOK * H_ * 2;
    _Float16* MI_h  = (_Float16*)p;      p += (size_t)M_TOK * H_ * 2;
    _Float16* MI_l  = (_Float16*)p;      p += (size_t)M_TOK * H_ * 2;
    _Float16* Wm1t_h = (_Float16*)p;     p += (size_t)H_ * H_ * 2;
    _Float16* Wm1t_l = (_Float16*)p;     p += (size_t)H_ * H_ * 2;
    _Float16* Wg1t_h = (_Float16*)p;     p += (size_t)H_ * H_ * 2;
    _Float16* Wg1t_l = (_Float16*)p;     p += (size_t)H_ * H_ * 2;
    _Float16* Wm2t_h = (_Float16*)p;     p += (size_t)H_ * H_ * 2;
    _Float16* Wm2t_l = (_Float16*)p;     p += (size_t)H_ * H_ * 2;
    _Float16* Ws1t_h = (_Float16*)p;     p += (size_t)4 * H2_ * H_ * 2;
    _Float16* Ws1t_l = (_Float16*)p;     p += (size_t)4 * H2_ * H_ * 2;

    hipMemsetAsync(d_out, 0, (size_t)out_size * sizeof(float), stream);
    hipMemsetAsync(accum, 0, 16 * sizeof(float), stream);

    const dim3 blk(256);

    // 1) activation split (hidden, image, genomic)
    APack ap;
    ap.g[0] = {hidden, hid_h, hid_l};
    ap.g[1] = {mimg,   img_h, img_l};
    ap.g[2] = {mgen,   gen_h, gen_l};
    asplit_kernel<<<dim3((M_TOK * H_) / (256 * 8), 1, 3), blk, 0, stream>>>(ap);

    // 2) weight split+transpose (scaled by 64)
    WPack wp;
    wp.g[0] = {Wm1, Wm1t_h, Wm1t_l, H_, H_};
    wp.g[1] = {Wg1, Wg1t_h, Wg1t_l, H_, H_};
    wp.g[2] = {Wm2, Wm2t_h, Wm2t_l, H_, H_};
    for (int m = 0; m < 4; ++m)
        wp.g[3 + m] = {Ws1 + (size_t)m * H_ * H2_,
                       Ws1t_h + (size_t)m * H2_ * H_,
                       Ws1t_l + (size_t)m * H2_ * H_, H_, H2_};
    wsplit_kernel<<<dim3(32, 32, 7), blk, 0, stream>>>(wp);

    // 3) batch A: input-only GEMMs (128x128 tiles, dbuf pipeline)
    GPack pa;
    pa.g[0] = {hid_h, hid_l, Wm1t_h, Wm1t_l, bm1, nullptr, T1_h, T1_l, H_, H_, 16, 1, 1};
    pa.g[1] = {hid_h, hid_l, Wg1t_h, Wg1t_l, bg1, G1, nullptr, nullptr, H_, H_, 16, 1, 0};
    pa.g[2] = {img_h, img_l, Ws1t_h + (size_t)0 * H2_ * H_, Ws1t_l + (size_t)0 * H2_ * H_,
               bs1 + 0 * H2_, S1 + (size_t)0 * M_TOK * H2_, nullptr, nullptr, H_, H2_, 8, 1, 0};
    pa.g[3] = {gen_h, gen_l, Ws1t_h + (size_t)1 * H2_ * H_, Ws1t_l + (size_t)1 * H2_ * H_,
               bs1 + 1 * H2_, S1 + (size_t)1 * M_TOK * H2_, nullptr, nullptr, H_, H2_, 8, 1, 0};
    gemm_mfma_kernel<<<dim3(64, 4, 4), blk, 0, stream>>>(pa);

    // 4) MISS = T1 @ Wm2 + bm2 (no relu), f16 h/l out
    GPack pb;
    pb.g[0] = {T1_h, T1_l, Wm2t_h, Wm2t_l, bm2, nullptr, MI_h, MI_l, H_, H_, 16, 0, 1};
    pb.g[1] = pb.g[0]; pb.g[2] = pb.g[0]; pb.g[3] = pb.g[0];
    gemm_mfma_kernel<<<dim3(64, 4, 1), blk, 0, stream>>>(pb);

    // 5) specialized routers on imputed modalities
    GPack pc;
    pc.g[0] = {MI_h, MI_l, Ws1t_h + (size_t)2 * H2_ * H_, Ws1t_l + (size_t)2 * H2_ * H_,
               bs1 + 2 * H2_, S1 + (size_t)2 * M_TOK * H2_, nullptr, nullptr, H_, H2_, 8, 1, 0};
    pc.g[1] = {MI_h, MI_l, Ws1t_h + (size_t)3 * H2_ * H_, Ws1t_l + (size_t)3 * H2_ * H_,
               bs1 + 3 * H2_, S1 + (size_t)3 * M_TOK * H2_, nullptr, nullptr, H_, H2_, 8, 1, 0};
    pc.g[2] = pc.g[0]; pc.g[3] = pc.g[0];
    gemm_mfma_kernel<<<dim3(64, 2, 2), blk, 0, stream>>>(pc);

    // 6) logit GEMMs (fp32)
    SPack sp;
    sp.g[0] = {G1, Wg2, bg2, GL, H_};
    for (int m = 0; m < 4; ++m)
        sp.g[1 + m] = {S1 + (size_t)m * M_TOK * H2_, Ws2 + (size_t)m * H2_ * E_,
                       bs2 + (size_t)m * E_, SL + (size_t)m * M_TOK * E_, H2_};
    gemm_n16_kernel<<<dim3(M_TOK / 16, 1, 5), blk, 0, stream>>>(sp);

    // 7) finalize
    router_kernel<<<M_TOK / 256, blk, 0, stream>>>(GL, SL, out, accum);
    aux_kernel<<<1, 64, 0, stream>>>(accum, out, (unsigned long long)out_size - 1);
}

// Round 8
// 707.095 us; speedup vs baseline: 1.2184x; 1.0386x over previous
//
#include <hip/hip_runtime.h>
#include <math.h>

// Problem constants (B=4, S=512, H=2048, E=16, K=4)
#define M_TOK 2048
#define H_    2048
#define H2_   1024
#define E_    16
#define CAP_  768
#define ALPHA_ 0.7f
#define WSCALE 64.0f
#define INV_WSCALE (1.0f / 64.0f)

typedef _Float16 half8 __attribute__((ext_vector_type(8)));
typedef float f32x4 __attribute__((ext_vector_type(4)));

typedef __attribute__((address_space(1))) const unsigned int* gas_ptr;
typedef __attribute__((address_space(3))) unsigned int* las_ptr;

__device__ __forceinline__ void load_lds16(const void* g, void* l) {
    __builtin_amdgcn_global_load_lds((gas_ptr)g, (las_ptr)l, 16, 0, 0);
}

// split 8 fp32 -> half8 hi + half8 lo
__device__ __forceinline__ void split8(const f32x4 a, const f32x4 b,
                                       half8* hi, half8* lo) {
#pragma unroll
    for (int i = 0; i < 4; ++i) {
        _Float16 h0 = (_Float16)a[i];
        (*hi)[i] = h0;
        (*lo)[i] = (_Float16)(a[i] - (float)h0);
        _Float16 h1 = (_Float16)b[i];
        (*hi)[i + 4] = h1;
        (*lo)[i + 4] = (_Float16)(b[i] - (float)h1);
    }
}

// ---------------------------------------------------------------------------
// Activation split: fp32 [M,K] -> f16 hi/lo [M,K]
// ---------------------------------------------------------------------------
struct ADesc { const float* A; _Float16* oh; _Float16* ol; };
struct APack { ADesc g[3]; };

__global__ __launch_bounds__(256) void asplit_kernel(APack pack)
{
    ADesc d;
    switch (blockIdx.z) {
        case 0: d = pack.g[0]; break;
        case 1: d = pack.g[1]; break;
        default: d = pack.g[2]; break;
    }
    const size_t i = ((size_t)blockIdx.x * 256 + threadIdx.x) * 8;
    f32x4 v0 = *(const f32x4*)(d.A + i);
    f32x4 v1 = *(const f32x4*)(d.A + i + 4);
    half8 h, l;
    split8(v0, v1, &h, &l);
    *(half8*)(d.oh + i) = h;
    *(half8*)(d.ol + i) = l;
}

// ---------------------------------------------------------------------------
// Weight split+transpose: W fp32 [K,N] -> Wt_h/Wt_l f16 [N,K], scaled by 64.
// ---------------------------------------------------------------------------
struct WDesc { const float* W; _Float16* oh; _Float16* ol; int K; int N; };
struct WPack { WDesc g[7]; };

__global__ __launch_bounds__(256) void wsplit_kernel(WPack pack)
{
    WDesc d;
    switch (blockIdx.z) {
        case 0: d = pack.g[0]; break;
        case 1: d = pack.g[1]; break;
        case 2: d = pack.g[2]; break;
        case 3: d = pack.g[3]; break;
        case 4: d = pack.g[4]; break;
        case 5: d = pack.g[5]; break;
        default: d = pack.g[6]; break;
    }
    const int n0 = blockIdx.y * 64;
    if (n0 >= d.N) return;
    const int k0 = blockIdx.x * 64;

    __shared__ float T[64][68];
    const int t = threadIdx.x;

    {
        const int kr = t >> 2;
        const int c0 = (t & 3) << 4;
        const float* src = d.W + (size_t)(k0 + kr) * d.N + n0 + c0;
        f32x4 v0 = *(const f32x4*)(src);
        f32x4 v1 = *(const f32x4*)(src + 4);
        f32x4 v2 = *(const f32x4*)(src + 8);
        f32x4 v3 = *(const f32x4*)(src + 12);
#pragma unroll
        for (int i = 0; i < 4; ++i) T[c0 + i][kr]      = v0[i];
#pragma unroll
        for (int i = 0; i < 4; ++i) T[c0 + 4 + i][kr]  = v1[i];
#pragma unroll
        for (int i = 0; i < 4; ++i) T[c0 + 8 + i][kr]  = v2[i];
#pragma unroll
        for (int i = 0; i < 4; ++i) T[c0 + 12 + i][kr] = v3[i];
    }
    __syncthreads();

    {
        const int n  = t >> 2;
        const int kj = (t & 3) << 4;
        half8 h0, l0, h1, l1;
        f32x4 u0 = *(const f32x4*)&T[n][kj];
        f32x4 u1 = *(const f32x4*)&T[n][kj + 4];
        f32x4 u2 = *(const f32x4*)&T[n][kj + 8];
        f32x4 u3 = *(const f32x4*)&T[n][kj + 12];
        u0 *= WSCALE; u1 *= WSCALE; u2 *= WSCALE; u3 *= WSCALE;
        split8(u0, u1, &h0, &l0);
        split8(u2, u3, &h1, &l1);
        const size_t o = (size_t)(n0 + n) * d.K + k0 + kj;
        *(half8*)(d.oh + o)     = h0;
        *(half8*)(d.oh + o + 8) = h1;
        *(half8*)(d.ol + o)     = l0;
        *(half8*)(d.ol + o + 8) = l1;
    }
}

// ---------------------------------------------------------------------------
// f16x3 MFMA GEMM, both operands pre-split f16 [rows,ldk].
// Block 128x128, 4 waves x 64x64, BK=32. Double-buffered LDS + raw barriers
// + vmcnt(8) (tile k+1 DMAs stay in flight across the barrier).
// mode 0: fp32 out (+bias,+relu); mode 1: f16 hi/lo out; mode 2: raw fp32
// partial (split-K: no bias/scale — combine kernel finishes).
// ---------------------------------------------------------------------------
struct GDesc {
    const _Float16* Ah; const _Float16* Al;
    const _Float16* Wh; const _Float16* Wl;
    const float* bias; float* Cf; _Float16* Ch; _Float16* Cl;
    int K; int ldk; int k0; int N; int ntn; int relu; int mode;
};
struct GPack { GDesc g[4]; };

__global__ __launch_bounds__(256) void gemm_mfma_kernel(GPack pack)
{
    GDesc d;
    switch (blockIdx.z) {
        case 0: d = pack.g[0]; break;
        case 1: d = pack.g[1]; break;
        case 2: d = pack.g[2]; break;
        default: d = pack.g[3]; break;
    }
    const int mt_ = blockIdx.x >> 2;
    const int nt_ = (blockIdx.y << 2) + (blockIdx.x & 3);
    if (nt_ >= d.ntn) return;
    const int bm = mt_ * 128, bn = nt_ * 128;
    const int K = d.K, N = d.N, ldk = d.ldk;

    // granule layout: slot g holds (row = g>>2, q = ((g&3) - (row>>1))&3);
    // fragment read of (row,q) at slot row*4 + ((q + (row>>1))&3)
    // -> every b128 access <=2-way (free). [verified 0 conflicts R4-R7]
    __shared__ _Float16 Ah_s[2][128 * 32];   // 8 KB x 2
    __shared__ _Float16 Al_s[2][128 * 32];
    __shared__ _Float16 Bh_s[2][128 * 32];
    __shared__ _Float16 Bl_s[2][128 * 32];

    const int tid  = threadIdx.x;
    const int lane = tid & 63;
    const int wave = tid >> 6;
    const int wm = wave >> 1, wn = wave & 1;

    // staging map (2 issues per thread per array; 512 granules)
    size_t a_goff[2], b_goff[2];
    int    s_lo[2];
#pragma unroll
    for (int is = 0; is < 2; ++is) {
        const int g = tid + (is << 8);
        const int row = g >> 2;
        const int q = ((g & 3) - (row >> 1)) & 3;
        a_goff[is] = (size_t)(bm + row) * ldk + d.k0 + q * 8;
        b_goff[is] = (size_t)(bn + row) * ldk + d.k0 + q * 8;
        s_lo[is]   = g * 8;
    }

    // fragment read offsets (mt/nt step of 16 rows keeps swizzle class)
    const int am0  = wm * 64 + (lane & 15);
    const int aoff = (am0 * 4 + (((lane >> 4) + (am0 >> 1)) & 3)) * 8;
    const int bn0  = wn * 64 + (lane & 15);
    const int boff = (bn0 * 4 + (((lane >> 4) + (bn0 >> 1)) & 3)) * 8;

    f32x4 acc[4][4];
#pragma unroll
    for (int i = 0; i < 4; ++i)
#pragma unroll
        for (int j = 0; j < 4; ++j) acc[i][j] = (f32x4)0.f;

    // 8 DMA issues per tile per thread (4 arrays x 2)
    auto issue_tile = [&](int kk, int c) {
#pragma unroll
        for (int is = 0; is < 2; ++is) {
            load_lds16(d.Ah + a_goff[is] + kk, &Ah_s[c][s_lo[is]]);
            load_lds16(d.Al + a_goff[is] + kk, &Al_s[c][s_lo[is]]);
            load_lds16(d.Wh + b_goff[is] + kk, &Bh_s[c][s_lo[is]]);
            load_lds16(d.Wl + b_goff[is] + kk, &Bl_s[c][s_lo[is]]);
        }
    };

    issue_tile(0, 0);

    const int niter = K >> 5;
    for (int it = 0; it < niter; ++it) {
        const int cur = it & 1;

        // #1: all waves done reading buf[cur^1]
        asm volatile("" ::: "memory");
        __builtin_amdgcn_s_barrier();

        if (it + 1 < niter) {
            issue_tile((it + 1) << 5, cur ^ 1);
            asm volatile("s_waitcnt vmcnt(8)" ::: "memory");
        } else {
            asm volatile("s_waitcnt vmcnt(0)" ::: "memory");
        }

        // #2: tile `it` visible to all waves
        __builtin_amdgcn_s_barrier();
        asm volatile("" ::: "memory");

        half8 fAh[4], fAl[4];
#pragma unroll
        for (int mt = 0; mt < 4; ++mt) {
            fAh[mt] = *(const half8*)&Ah_s[cur][aoff + mt * 512];
            fAl[mt] = *(const half8*)&Al_s[cur][aoff + mt * 512];
        }
#pragma unroll
        for (int nt = 0; nt < 4; ++nt) {
            half8 fBh = *(const half8*)&Bh_s[cur][boff + nt * 512];
            half8 fBl = *(const half8*)&Bl_s[cur][boff + nt * 512];
#pragma unroll
            for (int mt = 0; mt < 4; ++mt) {
                acc[mt][nt] = __builtin_amdgcn_mfma_f32_16x16x32_f16(
                    fAh[mt], fBh, acc[mt][nt], 0, 0, 0);
                acc[mt][nt] = __builtin_amdgcn_mfma_f32_16x16x32_f16(
                    fAh[mt], fBl, acc[mt][nt], 0, 0, 0);
                acc[mt][nt] = __builtin_amdgcn_mfma_f32_16x16x32_f16(
                    fAl[mt], fBh, acc[mt][nt], 0, 0, 0);
            }
        }
    }

    // epilogue: C/D layout col=lane&15, row=(lane>>4)*4+reg
    const int erow0 = bm + wm * 64 + ((lane >> 4) << 2);
    const int ecol0 = bn + wn * 64 + (lane & 15);
#pragma unroll
    for (int nt = 0; nt < 4; ++nt) {
        const int col = ecol0 + nt * 16;
        const float bb = (d.mode == 2) ? 0.f : d.bias[col];
#pragma unroll
        for (int mt = 0; mt < 4; ++mt) {
            f32x4 a = acc[mt][nt];
#pragma unroll
            for (int r = 0; r < 4; ++r) {
                const size_t o = (size_t)(erow0 + mt * 16 + r) * N + col;
                if (d.mode == 2) {
                    d.Cf[o] = a[r];             // raw partial (still x64)
                } else {
                    float v = a[r] * INV_WSCALE + bb;
                    if (d.relu) v = fmaxf(v, 0.f);
                    if (d.mode == 0) {
                        d.Cf[o] = v;
                    } else {
                        _Float16 h = (_Float16)v;
                        d.Ch[o] = h;
                        d.Cl[o] = (_Float16)(v - (float)h);
                    }
                }
            }
        }
    }
}

// ---------------------------------------------------------------------------
// Split-K combine: out = (P0+P1)*(1/64) + bias  (+relu / h-l split)
// mode 0: fp32 out (+relu); mode 1: f16 h/l out.
// ---------------------------------------------------------------------------
struct CDesc {
    const float* P0; const float* P1; const float* bias;
    float* Cf; _Float16* Ch; _Float16* Cl; int N; int relu; int mode;
};
struct CPack { CDesc g[2]; };

__global__ __launch_bounds__(256) void combine_kernel(CPack pack)
{
    CDesc d;
    switch (blockIdx.z) {
        case 0: d = pack.g[0]; break;
        default: d = pack.g[1]; break;
    }
    const size_t i = ((size_t)blockIdx.x * 256 + threadIdx.x) * 8;
    f32x4 a0 = *(const f32x4*)(d.P0 + i);
    f32x4 a1 = *(const f32x4*)(d.P0 + i + 4);
    f32x4 b0 = *(const f32x4*)(d.P1 + i);
    f32x4 b1 = *(const f32x4*)(d.P1 + i + 4);
    const int c0 = (int)(i & (size_t)(d.N - 1));
    f32x4 bb0 = *(const f32x4*)(d.bias + c0);
    f32x4 bb1 = *(const f32x4*)(d.bias + c0 + 4);
    f32x4 v0 = (a0 + b0) * INV_WSCALE + bb0;
    f32x4 v1 = (a1 + b1) * INV_WSCALE + bb1;
    if (d.relu) {
#pragma unroll
        for (int j = 0; j < 4; ++j) {
            v0[j] = fmaxf(v0[j], 0.f);
            v1[j] = fmaxf(v1[j], 0.f);
        }
    }
    if (d.mode == 0) {
        *(f32x4*)(d.Cf + i)     = v0;
        *(f32x4*)(d.Cf + i + 4) = v1;
    } else {
        half8 h, l;
        split8(v0, v1, &h, &l);
        *(half8*)(d.Ch + i) = h;
        *(half8*)(d.Cl + i) = l;
    }
}

// ---------------------------------------------------------------------------
// Batched skinny GEMM: C[M,16] = A[M,K] @ W[K,16] + bias[16]   (fp32)
// ---------------------------------------------------------------------------
struct SDesc { const float* A; const float* W; const float* bias; float* C; int K; };
struct SPack { SDesc g[5]; };

__global__ __launch_bounds__(256) void gemm_n16_kernel(SPack pack)
{
    SDesc d;
    switch (blockIdx.z) {
        case 0: d = pack.g[0]; break;
        case 1: d = pack.g[1]; break;
        case 2: d = pack.g[2]; break;
        case 3: d = pack.g[3]; break;
        default: d = pack.g[4]; break;
    }
    __shared__ float As[16][68];
    __shared__ float Ws[64][16];

    const int tid = threadIdx.x;
    const int e = tid & 15;
    const int r = tid >> 4;
    const int row0 = blockIdx.x * 16;

    const int lr  = tid >> 4;
    const int lk4 = (tid & 15) << 2;
    const int wk  = tid >> 2;
    const int we4 = (tid & 3) << 2;

    const int K = d.K;
    float acc = 0.f;
    for (int k0 = 0; k0 < K; k0 += 64) {
        float4 av = *(const float4*)&d.A[(size_t)(row0 + lr) * K + k0 + lk4];
        float4 wv = *(const float4*)&d.W[(size_t)(k0 + wk) * E_ + we4];
        if (k0) __syncthreads();
        *(float4*)&As[lr][lk4] = av;
        *(float4*)&Ws[wk][we4] = wv;
        __syncthreads();
#pragma unroll
        for (int kk = 0; kk < 64; kk += 4) {
            float4 a = *(const float4*)&As[r][kk];
            acc = fmaf(a.x, Ws[kk + 0][e], acc);
            acc = fmaf(a.y, Ws[kk + 1][e], acc);
            acc = fmaf(a.z, Ws[kk + 2][e], acc);
            acc = fmaf(a.w, Ws[kk + 3][e], acc);
        }
    }
    d.C[(size_t)(row0 + r) * E_ + e] = acc + d.bias[e];
}

// ---------------------------------------------------------------------------
// Router finalize
// ---------------------------------------------------------------------------
__device__ __forceinline__ void softmax16_acc(const float* __restrict__ lg,
                                              float w, float* __restrict__ p)
{
    float mx = lg[0];
#pragma unroll
    for (int e = 1; e < 16; ++e) mx = fmaxf(mx, lg[e]);
    float ex[16];
    float s = 0.f;
#pragma unroll
    for (int e = 0; e < 16; ++e) { ex[e] = expf(lg[e] - mx); s += ex[e]; }
    const float wi = w / s;
#pragma unroll
    for (int e = 0; e < 16; ++e) p[e] = fmaf(ex[e], wi, p[e]);
}

__global__ __launch_bounds__(256) void router_kernel(
    const float* __restrict__ GL, const float* __restrict__ SL,
    float* __restrict__ out, float* __restrict__ accum)
{
    const int t = blockIdx.x * 256 + threadIdx.x;

    float p[16];
#pragma unroll
    for (int e = 0; e < 16; ++e) p[e] = 0.f;

    softmax16_acc(GL + (size_t)t * E_, ALPHA_, p);
#pragma unroll
    for (int m = 0; m < 4; ++m)
        softmax16_acc(SL + ((size_t)m * M_TOK + t) * E_, (1.f - ALPHA_) * 0.5f, p);

    const size_t NTOT = (size_t)M_TOK * E_ * CAP_;
    float* probs_out = out + 2 * NTOT + (size_t)t * E_;
#pragma unroll
    for (int e = 0; e < 16; ++e) probs_out[e] = p[e];

    float red[16];
#pragma unroll
    for (int e = 0; e < 16; ++e) red[e] = p[e];
#pragma unroll
    for (int m = 1; m < 64; m <<= 1)
#pragma unroll
        for (int e = 0; e < 16; ++e) red[e] += __shfl_xor(red[e], m);
    const int lane = threadIdx.x & 63;
#pragma unroll
    for (int e = 0; e < 16; ++e)
        if (lane == e) atomicAdd(&accum[e], red[e]);

    float tmp[16];
#pragma unroll
    for (int e = 0; e < 16; ++e) tmp[e] = p[e];
    int   bi[4];
    float bv[4];
    float s4 = 0.f;
#pragma unroll
    for (int kk = 0; kk < 4; ++kk) {
        float best = -1.f; int besti = 0;
#pragma unroll
        for (int e = 0; e < 16; ++e)
            if (tmp[e] > best) { best = tmp[e]; besti = e; }
        bi[kk] = besti; bv[kk] = best; s4 += best;
        tmp[besti] = -1.f;
    }
    const float inv = 1.f / s4;
#pragma unroll
    for (int kk = 0; kk < 4; ++kk) {
        const size_t base = ((size_t)t * E_ + bi[kk]) * CAP_;
        out[base] = 1.0f;
        out[NTOT + base] = bv[kk] * inv;
    }
}

__global__ void aux_kernel(const float* __restrict__ accum,
                           float* __restrict__ out, unsigned long long pos)
{
    if (threadIdx.x == 0 && blockIdx.x == 0) {
        float s = 0.f;
#pragma unroll
        for (int e = 0; e < 16; ++e) {
            float m = accum[e] * (1.0f / (float)M_TOK);
            s += m * logf(m * (float)E_ + 1e-9f);
        }
        out[pos] = s;
    }
}

// ---------------------------------------------------------------------------
extern "C" void kernel_launch(void* const* d_in, const int* in_sizes, int n_in,
                              void* d_out, int out_size, void* d_ws, size_t ws_size,
                              hipStream_t stream)
{
    const float* hidden = (const float*)d_in[0];
    const float* mimg   = (const float*)d_in[1];
    const float* mgen   = (const float*)d_in[2];
    const float* Wg1 = (const float*)d_in[3];
    const float* bg1 = (const float*)d_in[4];
    const float* Wg2 = (const float*)d_in[5];
    const float* bg2 = (const float*)d_in[6];
    const float* Wm1 = (const float*)d_in[7];
    const float* bm1 = (const float*)d_in[8];
    const float* Wm2 = (const float*)d_in[9];
    const float* bm2 = (const float*)d_in[10];
    const float* Ws1 = (const float*)d_in[11];  // [4,H,H2]
    const float* bs1 = (const float*)d_in[12];  // [4,H2]
    const float* Ws2 = (const float*)d_in[13];  // [4,H2,E]
    const float* bs2 = (const float*)d_in[14];  // [4,E]

    float* out = (float*)d_out;

    // workspace layout
    char* p = (char*)d_ws;
    float* accum = (float*)p;            p += 256;
    float* G1    = (float*)p;            p += (size_t)M_TOK * H_ * 4;
    float* S1    = (float*)p;            p += (size_t)4 * M_TOK * H2_ * 4;
    float* GL    = (float*)p;            p += (size_t)M_TOK * E_ * 4;
    float* SL    = (float*)p;            p += (size_t)4 * M_TOK * E_ * 4;
    _Float16* hid_h = (_Float16*)p;      p += (size_t)M_TOK * H_ * 2;
    _Float16* hid_l = (_Float16*)p;      p += (size_t)M_TOK * H_ * 2;
    _Float16* img_h = (_Float16*)p;      p += (size_t)M_TOK * H_ * 2;
    _Float16* img_l = (_Float16*)p;      p += (size_t)M_TOK * H_ * 2;
    _Float16* gen_h = (_Float16*)p;      p += (size_t)M_TOK * H_ * 2;
    _Float16* gen_l = (_Float16*)p;      p += (size_t)M_TOK * H_ * 2;
    _Float16* T1_h  = (_Float16*)p;      p += (size_t)M_TOK * H_ * 2;
    _Float16* T1_l  = (_Float16*)p;      p += (size_t)M_TOK * H_ * 2;
    _Float16* MI_h  = (_Float16*)p;      p += (size_t)M_TOK * H_ * 2;
    _Float16* MI_l  = (_Float16*)p;      p += (size_t)M_TOK * H_ * 2;
    _Float16* Wm1t_h = (_Float16*)p;     p += (size_t)H_ * H_ * 2;
    _Float16* Wm1t_l = (_Float16*)p;     p += (size_t)H_ * H_ * 2;
    _Float16* Wg1t_h = (_Float16*)p;     p += (size_t)H_ * H_ * 2;
    _Float16* Wg1t_l = (_Float16*)p;     p += (size_t)H_ * H_ * 2;
    _Float16* Wm2t_h = (_Float16*)p;     p += (size_t)H_ * H_ * 2;
    _Float16* Wm2t_l = (_Float16*)p;     p += (size_t)H_ * H_ * 2;
    _Float16* Ws1t_h = (_Float16*)p;     p += (size_t)4 * H2_ * H_ * 2;
    _Float16* Ws1t_l = (_Float16*)p;     p += (size_t)4 * H2_ * H_ * 2;

    // split-K partial buffers ALIAS dead activation regions (stream-ordered):
    // hid_/img_ (dead after pa) hold pb partials [2048x2048]f32 each;
    // gen_/T1_ (dead after pa/pb) hold the four pc partials [2048x1024]f32.
    float* PB0 = (float*)hid_h;   // spans hid_h+hid_l = 16.8 MB
    float* PB1 = (float*)img_h;   // spans img_h+img_l
    float* PC00 = (float*)gen_h;  // 8.4 MB each
    float* PC01 = (float*)gen_l;
    float* PC10 = (float*)T1_h;
    float* PC11 = (float*)T1_l;

    hipMemsetAsync(d_out, 0, (size_t)out_size * sizeof(float), stream);
    hipMemsetAsync(accum, 0, 16 * sizeof(float), stream);

    const dim3 blk(256);

    // 1) activation split (hidden, image, genomic)
    APack ap;
    ap.g[0] = {hidden, hid_h, hid_l};
    ap.g[1] = {mimg,   img_h, img_l};
    ap.g[2] = {mgen,   gen_h, gen_l};
    asplit_kernel<<<dim3((M_TOK * H_) / (256 * 8), 1, 3), blk, 0, stream>>>(ap);

    // 2) weight split+transpose (scaled by 64)
    WPack wp;
    wp.g[0] = {Wm1, Wm1t_h, Wm1t_l, H_, H_};
    wp.g[1] = {Wg1, Wg1t_h, Wg1t_l, H_, H_};
    wp.g[2] = {Wm2, Wm2t_h, Wm2t_l, H_, H_};
    for (int m = 0; m < 4; ++m)
        wp.g[3 + m] = {Ws1 + (size_t)m * H_ * H2_,
                       Ws1t_h + (size_t)m * H2_ * H_,
                       Ws1t_l + (size_t)m * H2_ * H_, H_, H2_};
    wsplit_kernel<<<dim3(32, 32, 7), blk, 0, stream>>>(wp);

    // 3) batch A: input-only GEMMs (768 blocks)
    GPack pa;
    pa.g[0] = {hid_h, hid_l, Wm1t_h, Wm1t_l, bm1, nullptr, T1_h, T1_l,
               H_, H_, 0, H_, 16, 1, 1};
    pa.g[1] = {hid_h, hid_l, Wg1t_h, Wg1t_l, bg1, G1, nullptr, nullptr,
               H_, H_, 0, H_, 16, 1, 0};
    pa.g[2] = {img_h, img_l, Ws1t_h + (size_t)0 * H2_ * H_, Ws1t_l + (size_t)0 * H2_ * H_,
               bs1 + 0 * H2_, S1 + (size_t)0 * M_TOK * H2_, nullptr, nullptr,
               H_, H_, 0, H2_, 8, 1, 0};
    pa.g[3] = {gen_h, gen_l, Ws1t_h + (size_t)1 * H2_ * H_, Ws1t_l + (size_t)1 * H2_ * H_,
               bs1 + 1 * H2_, S1 + (size_t)1 * M_TOK * H2_, nullptr, nullptr,
               H_, H_, 0, H2_, 8, 1, 0};
    gemm_mfma_kernel<<<dim3(64, 4, 4), blk, 0, stream>>>(pa);

    // 4) T1 @ Wm2: split-K=2 -> raw partials (512 blocks, 2/CU)
    GPack pb;
    pb.g[0] = {T1_h, T1_l, Wm2t_h, Wm2t_l, nullptr, PB0, nullptr, nullptr,
               H_ / 2, H_, 0,      H_, 16, 0, 2};
    pb.g[1] = {T1_h, T1_l, Wm2t_h, Wm2t_l, nullptr, PB1, nullptr, nullptr,
               H_ / 2, H_, H_ / 2, H_, 16, 0, 2};
    pb.g[2] = pb.g[0]; pb.g[3] = pb.g[0];
    gemm_mfma_kernel<<<dim3(64, 4, 2), blk, 0, stream>>>(pb);

    // 4b) combine -> MISS f16 h/l (no relu)
    CPack cb;
    cb.g[0] = {PB0, PB1, bm2, nullptr, MI_h, MI_l, H_, 0, 1};
    cb.g[1] = cb.g[0];
    combine_kernel<<<dim3((M_TOK * H_) / (256 * 8), 1, 1), blk, 0, stream>>>(cb);

    // 5) specialized routers on MISS: 2 gemms x split-K=2 (512 blocks)
    GPack pc;
    pc.g[0] = {MI_h, MI_l, Ws1t_h + (size_t)2 * H2_ * H_, Ws1t_l + (size_t)2 * H2_ * H_,
               nullptr, PC00, nullptr, nullptr, H_ / 2, H_, 0,      H2_, 8, 0, 2};
    pc.g[1] = {MI_h, MI_l, Ws1t_h + (size_t)2 * H2_ * H_, Ws1t_l + (size_t)2 * H2_ * H_,
               nullptr, PC01, nullptr, nullptr, H_ / 2, H_, H_ / 2, H2_, 8, 0, 2};
    pc.g[2] = {MI_h, MI_l, Ws1t_h + (size_t)3 * H2_ * H_, Ws1t_l + (size_t)3 * H2_ * H_,
               nullptr, PC10, nullptr, nullptr, H_ / 2, H_, 0,      H2_, 8, 0, 2};
    pc.g[3] = {MI_h, MI_l, Ws1t_h + (size_t)3 * H2_ * H_, Ws1t_l + (size_t)3 * H2_ * H_,
               nullptr, PC11, nullptr, nullptr, H_ / 2, H_, H_ / 2, H2_, 8, 0, 2};
    gemm_mfma_kernel<<<dim3(64, 2, 4), blk, 0, stream>>>(pc);

    // 5b) combine -> S1[2], S1[3] fp32 (+bias +relu)
    CPack cc;
    cc.g[0] = {PC00, PC01, bs1 + 2 * H2_, S1 + (size_t)2 * M_TOK * H2_,
               nullptr, nullptr, H2_, 1, 0};
    cc.g[1] = {PC10, PC11, bs1 + 3 * H2_, S1 + (size_t)3 * M_TOK * H2_,
               nullptr, nullptr, H2_, 1, 0};
    combine_kernel<<<dim3((M_TOK * H2_) / (256 * 8), 1, 2), blk, 0, stream>>>(cc);

    // 6) logit GEMMs (fp32)
    SPack sp;
    sp.g[0] = {G1, Wg2, bg2, GL, H_};
    for (int m = 0; m < 4; ++m)
        sp.g[1 + m] = {S1 + (size_t)m * M_TOK * H2_, Ws2 + (size_t)m * H2_ * E_,
                       bs2 + (size_t)m * E_, SL + (size_t)m * M_TOK * E_, H2_};
    gemm_n16_kernel<<<dim3(M_TOK / 16, 1, 5), blk, 0, stream>>>(sp);

    // 7) finalize
    router_kernel<<<M_TOK / 256, blk, 0, stream>>>(GL, SL, out, accum);
    aux_kernel<<<1, 64, 0, stream>>>(accum, out, (unsigned long long)out_size - 1);
}